// Round 10
// baseline (625.093 us; speedup 1.0000x reference)
//
#include <hip/hip_runtime.h>
#include <hip/hip_bf16.h>
#include <math.h>

#define TT 77
#define MTOT 32768

typedef __attribute__((ext_vector_type(8))) short bf16x8;
typedef __attribute__((ext_vector_type(4))) float floatx4;

#define GPTR(p) ((const __attribute__((address_space(1))) void*)(p))
#define LPTR(p) ((__attribute__((address_space(3))) void*)(p))

__device__ __forceinline__ float wred_sum(float v) {
#pragma unroll
  for (int o = 32; o >= 1; o >>= 1) v += __shfl_xor(v, o, 64);
  return v;
}

__device__ __forceinline__ unsigned short f2bf(float f) {
  unsigned int u = __float_as_uint(f);
  unsigned int r = (u + 0x7fffu + ((u >> 16) & 1u)) >> 16;
  return (unsigned short)r;
}
__device__ __forceinline__ float bf2f(unsigned short h) {
  return __uint_as_float(((unsigned int)h) << 16);
}
// hw packed RTNE f32->bf16 (bit-identical to f2bf), 2 values in 1 inst
__device__ __forceinline__ unsigned int cvt2bf(float a, float b) {
  unsigned int r;
  asm("v_cvt_pk_bf16_f32 %0, %1, %2" : "=v"(r) : "v"(a), "v"(b));
  return r;
}

// fast erf-based GELU: Abramowitz-Stegun 7.1.26, |err| <= 1.5e-7 (way below bf16 lsb)
__device__ __forceinline__ float fast_gelu(float o) {
  const float z = fabsf(o) * 0.70710678118654752f;
  const float t = __builtin_amdgcn_rcpf(fmaf(0.3275911f, z, 1.0f));
  float p = fmaf(1.061405429f, t, -1.453152027f);
  p = fmaf(p, t, 1.421413741f);
  p = fmaf(p, t, -0.284496736f);
  p = fmaf(p, t, 0.254829592f);
  p = p * t;
  const float erfz = fmaf(-p, __expf(-z * z), 1.0f);   // erf(|o|/sqrt2)
  const float s = __builtin_copysignf(erfz, o);
  return 0.5f * o * (1.0f + s);
}

__device__ __forceinline__ float fast_sigmoid(float o) {
  return __builtin_amdgcn_rcpf(1.0f + __expf(-o));
}

// ---------------- LayerNorm over rows of 512 -> bf16 out (one wave per row) ---
__global__ __launch_bounds__(256)
void ln_bf16_kernel(const float* __restrict__ in, const float* __restrict__ gw,
                    const float* __restrict__ gb, unsigned short* __restrict__ out) {
  const int wv = threadIdx.x >> 6, lane = threadIdx.x & 63;
  const size_t row = (size_t)blockIdx.x * 4 + wv;
  const float* p = in + row * 512 + lane * 8;
  float4 a = *(const float4*)p;
  float4 b = *(const float4*)(p + 4);
  float s = a.x + a.y + a.z + a.w + b.x + b.y + b.z + b.w;
  float mu = wred_sum(s) * (1.0f / 512.0f);
  float d[8] = {a.x - mu, a.y - mu, a.z - mu, a.w - mu,
                b.x - mu, b.y - mu, b.z - mu, b.w - mu};
  float ss = 0.f;
#pragma unroll
  for (int i = 0; i < 8; ++i) ss = fmaf(d[i], d[i], ss);
  float var = wred_sum(ss) * (1.0f / 512.0f);
  float rstd = rsqrtf(var + 1e-5f);
  float4 w0 = *(const float4*)(gw + lane * 8);
  float4 w1 = *(const float4*)(gw + lane * 8 + 4);
  float4 c0 = *(const float4*)(gb + lane * 8);
  float4 c1 = *(const float4*)(gb + lane * 8 + 4);
  float o[8];
  o[0] = d[0] * rstd * w0.x + c0.x;  o[1] = d[1] * rstd * w0.y + c0.y;
  o[2] = d[2] * rstd * w0.z + c0.z;  o[3] = d[3] * rstd * w0.w + c0.w;
  o[4] = d[4] * rstd * w1.x + c1.x;  o[5] = d[5] * rstd * w1.y + c1.y;
  o[6] = d[6] * rstd * w1.z + c1.z;  o[7] = d[7] * rstd * w1.w + c1.w;
  __align__(16) unsigned short ob[8];
#pragma unroll
  for (int i = 0; i < 8; ++i) ob[i] = f2bf(o[i]);
  *(uint4*)(out + row * 512 + lane * 8) = *(const uint4*)ob;
}

// ---------------- zero the per-row ||q||^2 and conf accumulators --------------
__global__ __launch_bounds__(256)
void zero_acc_kernel(float* __restrict__ ssq, float* __restrict__ conf) {
  const int i = blockIdx.x * 256 + threadIdx.x;
  ssq[i] = 0.0f;
  conf[i] = 0.0f;
}

// ---------------- weight transpose + bf16 convert: W[K,N] -> WT[N,K] ----------
__global__ __launch_bounds__(256)
void transpose_bf16_kernel(const float* __restrict__ W, unsigned short* __restrict__ WTb,
                           int K, int N) {
  __shared__ float s[32][33];
  const int tx = threadIdx.x & 31, ty = threadIdx.x >> 5;  // ty 0..7
  const int n0 = blockIdx.x * 32, k0 = blockIdx.y * 32;
#pragma unroll
  for (int j = 0; j < 4; ++j)
    s[ty + 8 * j][tx] = W[(size_t)(k0 + ty + 8 * j) * N + n0 + tx];
  __syncthreads();
#pragma unroll
  for (int j = 0; j < 4; ++j)
    WTb[(size_t)(n0 + ty + 8 * j) * K + k0 + tx] = f2bf(s[tx][ty + 8 * j]);
}

// ---------------- pair transpose: W[K,N] -> hi/lo split bf16 WT[N,K] ----------
__global__ __launch_bounds__(256)
void transpose_pair_kernel(const float* __restrict__ W,
                           unsigned short* __restrict__ WTh,
                           unsigned short* __restrict__ WTl, int K, int N) {
  __shared__ float s[32][33];
  const int tx = threadIdx.x & 31, ty = threadIdx.x >> 5;  // ty 0..7
  const int n0 = blockIdx.x * 32, k0 = blockIdx.y * 32;
#pragma unroll
  for (int j = 0; j < 4; ++j)
    s[ty + 8 * j][tx] = W[(size_t)(k0 + ty + 8 * j) * N + n0 + tx];
  __syncthreads();
#pragma unroll
  for (int j = 0; j < 4; ++j) {
    const float a = s[tx][ty + 8 * j];
    const unsigned short hi = f2bf(a);
    WTh[(size_t)(n0 + ty + 8 * j) * K + k0 + tx] = hi;
    WTl[(size_t)(n0 + ty + 8 * j) * K + k0 + tx] = f2bf(a - bf2f(hi));
  }
}

// ---------------- text -> hi/lo bf16 split (rows 616..639 zeroed) + pad mask --
__global__ __launch_bounds__(256)
void text_cvt_kernel(const float* __restrict__ text,
                     unsigned short* __restrict__ thi,
                     unsigned short* __restrict__ tlo,
                     float* __restrict__ negm) {
  const int wv = threadIdx.x >> 6, lane = threadIdx.x & 63;
  const int row = blockIdx.x * 4 + wv;       // 0..639
  if (row >= 616) {
    const uint4 z = {0u, 0u, 0u, 0u};
    *(uint4*)(thi + (size_t)row * 512 + lane * 8) = z;
    *(uint4*)(tlo + (size_t)row * 512 + lane * 8) = z;
    return;
  }
  const float* p = text + (size_t)row * 512 + lane * 8;
  float4 a = *(const float4*)p;
  float4 b = *(const float4*)(p + 4);
  float v[8] = {a.x, a.y, a.z, a.w, b.x, b.y, b.z, b.w};
  float ab = 0.f;
#pragma unroll
  for (int i = 0; i < 8; ++i) ab += fabsf(v[i]);
  ab = wred_sum(ab);
  __align__(16) unsigned short hb[8];
  __align__(16) unsigned short lb[8];
#pragma unroll
  for (int i = 0; i < 8; ++i) {
    hb[i] = f2bf(v[i]);
    lb[i] = f2bf(v[i] - bf2f(hb[i]));
  }
  *(uint4*)(thi + (size_t)row * 512 + lane * 8) = *(const uint4*)hb;
  *(uint4*)(tlo + (size_t)row * 512 + lane * 8) = *(const uint4*)lb;
  if (lane == 0) {
    const int bb = row / 77, t = row - bb * 77;
    negm[bb * 80 + t] = (ab <= 1e-6f) ? -INFINITY : 0.0f;
  }
}

// ---------------- kv projection GEMM, split-bf16 (~fp32 exact) ----------------
__global__ __launch_bounds__(256)
void kv_gemm(const unsigned short* __restrict__ AH,
             const unsigned short* __restrict__ AL,
             const unsigned short* __restrict__ BH,
             const unsigned short* __restrict__ BL,
             const float* __restrict__ bk, const float* __restrict__ bv,
             float* __restrict__ outp) {
  const int K = 512;
  __shared__ __align__(16) unsigned short AsH[128 * 32];
  __shared__ __align__(16) unsigned short AsL[128 * 32];
  __shared__ __align__(16) unsigned short BsH[128 * 32];
  __shared__ __align__(16) unsigned short BsL[128 * 32];
  const int tid = threadIdx.x;
  const int wid = tid >> 6, lane = tid & 63;
  const int wr = wid >> 1, wc = wid & 1;
  const int m16 = lane & 15, quad = lane >> 4;
  const int row0 = blockIdx.y * 128, col0 = blockIdx.x * 128;

  const floatx4 zero4 = {0.f, 0.f, 0.f, 0.f};
  floatx4 acc[4][4];
#pragma unroll
  for (int i = 0; i < 4; ++i)
#pragma unroll
    for (int j = 0; j < 4; ++j) acc[i][j] = zero4;

  const int srow = tid >> 2;
  const int schunk = (tid & 3) ^ (srow & 3);
  const unsigned short* AgH = AH + (size_t)(row0 + srow) * K + schunk * 8;
  const unsigned short* AgL = AL + (size_t)(row0 + srow) * K + schunk * 8;
  const unsigned short* BgH = BH + (size_t)(col0 + srow) * K + schunk * 8;
  const unsigned short* BgL = BL + (size_t)(col0 + srow) * K + schunk * 8;
  char* AsHB = (char*)AsH + tid * 16;
  char* AsLB = (char*)AsL + tid * 16;
  char* BsHB = (char*)BsH + tid * 16;
  char* BsLB = (char*)BsL + tid * 16;
  const int rq = quad ^ (m16 & 3);
  const int aOfs = (wr * 64 + m16) * 32 + rq * 8;
  const int bOfs = (wc * 64 + m16) * 32 + rq * 8;

  for (int k0 = 0; k0 < K; k0 += 32) {
    __syncthreads();
    __builtin_amdgcn_global_load_lds(GPTR(AgH + k0), LPTR(AsHB), 16, 0, 0);
    __builtin_amdgcn_global_load_lds(GPTR(AgH + (size_t)64 * K + k0), LPTR(AsHB + 4096), 16, 0, 0);
    __builtin_amdgcn_global_load_lds(GPTR(AgL + k0), LPTR(AsLB), 16, 0, 0);
    __builtin_amdgcn_global_load_lds(GPTR(AgL + (size_t)64 * K + k0), LPTR(AsLB + 4096), 16, 0, 0);
    __builtin_amdgcn_global_load_lds(GPTR(BgH + k0), LPTR(BsHB), 16, 0, 0);
    __builtin_amdgcn_global_load_lds(GPTR(BgH + (size_t)64 * K + k0), LPTR(BsHB + 4096), 16, 0, 0);
    __builtin_amdgcn_global_load_lds(GPTR(BgL + k0), LPTR(BsLB), 16, 0, 0);
    __builtin_amdgcn_global_load_lds(GPTR(BgL + (size_t)64 * K + k0), LPTR(BsLB + 4096), 16, 0, 0);
    __syncthreads();
    bf16x8 afH[4], afL[4], bfH[4], bfL[4];
#pragma unroll
    for (int i = 0; i < 4; ++i) {
      afH[i] = *(const bf16x8*)(AsH + aOfs + i * 16 * 32);
      afL[i] = *(const bf16x8*)(AsL + aOfs + i * 16 * 32);
      bfH[i] = *(const bf16x8*)(BsH + bOfs + i * 16 * 32);
      bfL[i] = *(const bf16x8*)(BsL + bOfs + i * 16 * 32);
    }
#pragma unroll
    for (int mi = 0; mi < 4; ++mi)
#pragma unroll
      for (int ni = 0; ni < 4; ++ni) {
        acc[mi][ni] = __builtin_amdgcn_mfma_f32_16x16x32_bf16(afH[mi], bfH[ni], acc[mi][ni], 0, 0, 0);
        acc[mi][ni] = __builtin_amdgcn_mfma_f32_16x16x32_bf16(afH[mi], bfL[ni], acc[mi][ni], 0, 0, 0);
        acc[mi][ni] = __builtin_amdgcn_mfma_f32_16x16x32_bf16(afL[mi], bfH[ni], acc[mi][ni], 0, 0, 0);
      }
  }

  const float* bp = (col0 < 512) ? bk : bv;
  const int cbase = (col0 < 512) ? col0 : col0 - 512;
  float bb[4];
#pragma unroll
  for (int ni = 0; ni < 4; ++ni) bb[ni] = bp[cbase + wc * 64 + ni * 16 + m16];
#pragma unroll
  for (int mi = 0; mi < 4; ++mi)
#pragma unroll
    for (int r = 0; r < 4; ++r) {
      const int row = row0 + wr * 64 + mi * 16 + quad * 4 + r;
#pragma unroll
      for (int ni = 0; ni < 4; ++ni) {
        const int col = col0 + wc * 64 + ni * 16 + m16;
        outp[(size_t)row * 1024 + col] = acc[mi][ni][r] + bb[ni];
      }
    }
}

// ---------------- k rows: L2-normalize -> head-major bf16 ---------------------
__global__ __launch_bounds__(256)
void knorm_kernel(const float* __restrict__ KV,     // [640,1024], k = cols 0..511
                  unsigned short* __restrict__ khb) {  // [B,8,80,64]
  const int wv = threadIdx.x >> 6, lane = threadIdx.x & 63;
  const int row = blockIdx.x * 4 + wv;   // 0..615
  const float* p = KV + (size_t)row * 1024 + lane * 8;
  float4 a = *(const float4*)p;
  float4 b = *(const float4*)(p + 4);
  float v[8] = {a.x, a.y, a.z, a.w, b.x, b.y, b.z, b.w};
  float ss = 0.f;
#pragma unroll
  for (int i = 0; i < 8; ++i) ss = fmaf(v[i], v[i], ss);
  ss = wred_sum(ss);
  const float sc = 1.0f / fmaxf(sqrtf(ss), 1e-6f);
  const int bb = row / 77, t = row - bb * 77;
  const int c = lane * 8, h = c >> 6, d = c & 63;
  __align__(16) unsigned short ob[8];
#pragma unroll
  for (int i = 0; i < 8; ++i) ob[i] = f2bf(v[i] * sc);
  *(uint4*)(khb + (((size_t)bb * 8 + h) * 80 + t) * 64 + d) = *(const uint4*)ob;
}

// ---------------- zero the k pad rows (t = 77..79) + -inf negmask there -------
__global__ __launch_bounds__(256)
void kpad_zero_kernel(unsigned short* __restrict__ khb, float* __restrict__ negm) {
  const int i = blockIdx.x * 256 + threadIdx.x;
  const int bh = i / 192, rem = i - bh * 192;
  const int t = 77 + rem / 64, d = rem & 63;
  khb[(((size_t)bh) * 80 + t) * 64 + d] = 0;
  if (i < 24) negm[(i / 3) * 80 + 77 + (i % 3)] = -INFINITY;
}

// ---------------- FUSED: sim (MFMA) -> LDS -> topk/softmax/conf/PV ------------
__global__ __launch_bounds__(256)
void sim_attn_kernel(const unsigned short* __restrict__ qnb,   // [32768,512] bf16 q
                     const unsigned short* __restrict__ khb,   // [64,80,64] bf16
                     const float* __restrict__ negm,           // [8,80]
                     const float* __restrict__ ssq,            // [32768] ||q||^2
                     const float* __restrict__ logit_scale,
                     const float* __restrict__ vf,             // KV+512, stride 1024
                     unsigned short* __restrict__ alignedb,    // [32768,512] bf16
                     float* __restrict__ confacc) {            // [32768] (pre-zeroed)
  __shared__ __align__(16) char lbuf[128 * 81 * 4];   // 41472 B; unioned
  unsigned short* As = (unsigned short*)lbuf;         // [128*72] phase 1
  unsigned short* Bs = As + 128 * 72;                 // [80*72]  phase 1
  float* simt = (float*)lbuf;                         // [128][81] phase 2

  const int bh = blockIdx.y;           // b*8+h
  const int b = bh >> 3, h = bh & 7;
  const int row0 = blockIdx.x * 128;   // within 4096
  const int tid = threadIdx.x;

  {
    const int r = tid >> 1, half = tid & 1;
    const unsigned short* src = qnb + ((size_t)b * 4096 + row0 + r) * 512 + h * 64 + half * 32;
    unsigned short* dst = As + r * 72 + half * 32;
    *(uint4*)dst = *(const uint4*)src;
    *(uint4*)(dst + 8) = *(const uint4*)(src + 8);
    *(uint4*)(dst + 16) = *(const uint4*)(src + 16);
    *(uint4*)(dst + 24) = *(const uint4*)(src + 24);
  }
  if (tid < 160) {
    const int r = tid >> 1, half = tid & 1;
    const unsigned short* src = khb + ((size_t)bh * 80 + r) * 64 + half * 32;
    unsigned short* dst = Bs + r * 72 + half * 32;
    *(uint4*)dst = *(const uint4*)src;
    *(uint4*)(dst + 8) = *(const uint4*)(src + 8);
    *(uint4*)(dst + 16) = *(const uint4*)(src + 16);
    *(uint4*)(dst + 24) = *(const uint4*)(src + 24);
  }
  __syncthreads();

  const int w = tid >> 6, lane = tid & 63;
  const int m16 = lane & 15, quad = lane >> 4;
  const unsigned short* aBase = As + (w * 32 + m16) * 72 + quad * 8;
  const unsigned short* bBase = Bs + m16 * 72 + quad * 8;
  bf16x8 af[2][2], bf[5][2];
#pragma unroll
  for (int mi = 0; mi < 2; ++mi)
#pragma unroll
    for (int kk = 0; kk < 2; ++kk)
      af[mi][kk] = *(const bf16x8*)(aBase + mi * 16 * 72 + kk * 32);
#pragma unroll
  for (int ni = 0; ni < 5; ++ni)
#pragma unroll
    for (int kk = 0; kk < 2; ++kk)
      bf[ni][kk] = *(const bf16x8*)(bBase + ni * 16 * 72 + kk * 32);
  __syncthreads();   // all frag reads done before LDS reuse

  const floatx4 zero4 = {0.f, 0.f, 0.f, 0.f};
  floatx4 acc[2][5];
#pragma unroll
  for (int mi = 0; mi < 2; ++mi)
#pragma unroll
    for (int ni = 0; ni < 5; ++ni) acc[mi][ni] = zero4;
#pragma unroll
  for (int kk = 0; kk < 2; ++kk)
#pragma unroll
    for (int mi = 0; mi < 2; ++mi)
#pragma unroll
      for (int ni = 0; ni < 5; ++ni)
        acc[mi][ni] = __builtin_amdgcn_mfma_f32_16x16x32_bf16(af[mi][kk], bf[ni][kk], acc[mi][ni], 0, 0, 0);

  const float ls = fminf(fmaxf(logit_scale[0], -2.0f), 2.0f);
  const float scale = expf(ls) * 0.125f;
  float nm[5];
#pragma unroll
  for (int ni = 0; ni < 5; ++ni) nm[ni] = negm[b * 80 + ni * 16 + m16];
#pragma unroll
  for (int mi = 0; mi < 2; ++mi)
#pragma unroll
    for (int r = 0; r < 4; ++r) {
      const int lr = w * 32 + quad * 4 + mi * 16 + r;   // 0..127
      const float ssv = ssq[(size_t)b * 4096 + row0 + lr];
      const float nsc = scale / fmaxf(sqrtf(ssv), 1e-6f);
#pragma unroll
      for (int ni = 0; ni < 5; ++ni)
        simt[lr * 81 + ni * 16 + m16] = acc[mi][ni][r] * nsc + nm[ni];
    }
  __syncthreads();

  // ---- phase 2: per (row, half) top-3 + closed-form softmax + PV ----
  const int lr = tid >> 1, half = tid & 1;
  const int n = row0 + lr;
  const float* sp = simt + lr * 81;

  float m1 = -INFINITY, m2 = -INFINITY, m3 = -INFINITY, m4 = -INFINITY;
  int a1 = 0, a2 = 0, a3 = 0;
  for (int t = 0; t < 80; ++t) {
    const float v = sp[t];
    const bool c1 = v > m1, c2 = v > m2, c3 = v > m3, c4 = v > m4;
    m4 = c4 ? (c3 ? m3 : v) : m4;
    m3 = c3 ? (c2 ? m2 : v) : m3;
    a3 = c3 ? (c2 ? a2 : t) : a3;
    m2 = c2 ? (c1 ? m1 : v) : m2;
    a2 = c2 ? (c1 ? a1 : t) : a2;
    m1 = c1 ? v : m1;
    a1 = c1 ? t : a1;
  }

  const bool dead = (m1 == -INFINITY);
  if (dead) m1 = 0.0f;
  const bool tie = (!dead) && ((m1 == m2) || (m2 == m3) || (m3 == m4));

  const float d2 = m2 - m1, d3 = m3 - m1;
  const float e2 = __expf(d2), e3 = __expf(d3);   // exp(-inf)=0
  float s0 = 1.0f + e2 + e3;
  float s1 = ((e2 > 0.f) ? e2 * d2 : 0.f) + ((e3 > 0.f) ? e3 * d3 : 0.f);
  float cntf = 1.0f + ((e2 > 0.f) ? 1.f : 0.f) + ((e3 > 0.f) ? 1.f : 0.f);

  unsigned short* op = alignedb + ((size_t)b * 4096 + n) * 512 + h * 64 + half * 32;

  if (tie) {
    s0 = 0.f; s1 = 0.f; cntf = 0.f;
    float4 acc2[8];
#pragma unroll
    for (int i = 0; i < 8; ++i) acc2[i] = (float4){0.f, 0.f, 0.f, 0.f};
    for (int t = 0; t < 80; ++t) {
      const float v = sp[t];
      if (v >= m3) {
        const float e = expf(v - m1);
        if (e > 0.f) {
          s0 += e; s1 = fmaf(e, v - m1, s1); cntf += 1.f;
          const float4* vp = (const float4*)(vf + (size_t)(b * 77 + t) * 1024 + h * 64 + half * 32);
#pragma unroll
          for (int i = 0; i < 8; ++i) {
            const float4 x = vp[i];
            acc2[i].x = fmaf(e, x.x, acc2[i].x);
            acc2[i].y = fmaf(e, x.y, acc2[i].y);
            acc2[i].z = fmaf(e, x.z, acc2[i].z);
            acc2[i].w = fmaf(e, x.w, acc2[i].w);
          }
        }
      }
    }
    const float invt = 1.0f / s0;
#pragma unroll
    for (int i = 0; i < 4; ++i) {
      const float4 lo = acc2[2 * i], hi = acc2[2 * i + 1];
      uint4 pk;
      pk.x = cvt2bf(lo.x * invt, lo.y * invt);
      pk.y = cvt2bf(lo.z * invt, lo.w * invt);
      pk.z = cvt2bf(hi.x * invt, hi.y * invt);
      pk.w = cvt2bf(hi.z * invt, hi.w * invt);
      *(uint4*)(op + i * 8) = pk;
    }
  } else {
    const float inv0 = 1.0f / s0;
    const float wA = dead ? 0.f : inv0;
    const float wB = e2 * inv0, wC = e3 * inv0;
    const float* v1p = vf + (size_t)(b * 77 + a1) * 1024 + h * 64 + half * 32;
    const float* v2p = vf + (size_t)(b * 77 + a2) * 1024 + h * 64 + half * 32;
    const float* v3p = vf + (size_t)(b * 77 + a3) * 1024 + h * 64 + half * 32;
#pragma unroll
    for (int i = 0; i < 4; ++i) {
      const float4 x0 = ((const float4*)v1p)[2 * i];
      const float4 x1 = ((const float4*)v1p)[2 * i + 1];
      const float4 y0 = ((const float4*)v2p)[2 * i];
      const float4 y1 = ((const float4*)v2p)[2 * i + 1];
      const float4 z0 = ((const float4*)v3p)[2 * i];
      const float4 z1 = ((const float4*)v3p)[2 * i + 1];
      float4 r0, r1;
      r0.x = fmaf(wC, z0.x, fmaf(wB, y0.x, wA * x0.x));
      r0.y = fmaf(wC, z0.y, fmaf(wB, y0.y, wA * x0.y));
      r0.z = fmaf(wC, z0.z, fmaf(wB, y0.z, wA * x0.z));
      r0.w = fmaf(wC, z0.w, fmaf(wB, y0.w, wA * x0.w));
      r1.x = fmaf(wC, z1.x, fmaf(wB, y1.x, wA * x1.x));
      r1.y = fmaf(wC, z1.y, fmaf(wB, y1.y, wA * x1.y));
      r1.z = fmaf(wC, z1.z, fmaf(wB, y1.z, wA * x1.z));
      r1.w = fmaf(wC, z1.w, fmaf(wB, y1.w, wA * x1.w));
      uint4 pk;
      pk.x = cvt2bf(r0.x, r0.y);
      pk.y = cvt2bf(r0.z, r0.w);
      pk.z = cvt2bf(r1.x, r1.y);
      pk.w = cvt2bf(r1.z, r1.w);
      *(uint4*)(op + i * 8) = pk;
    }
  }

  if (half == 0) {
    const float inv = 1.0f / s0;
    const float entn = (__logf(s0) - s1 * inv) + (77.0f - cntf) * 1.8420681e-7f;
    const float ent = fmaxf(entn / __logf(fmaxf(cntf, 2.0f)), 0.0f);
    float conf_h = fminf(fmaxf(inv * (1.0f - ent), 0.0f), 1.0f);
    if (dead) conf_h = 0.f;
    atomicAdd(confacc + (size_t)b * 4096 + n, conf_h * 0.125f);
  }
}

// ---------------- bf16 MFMA GEMM, BK=64, 2-phase double-buffered pipeline -----
// LDS tiles [2][128][64] ushort; chunk-XOR swizzle (chunk ^= row&7) applied at
// the global source (global_load_lds writes linearly) and at ds_read.
// B staged column-permuted (LDS row holds WT row 64a+4d+c) so each lane's 4
// outputs are CONSECUTIVE columns -> vector stores/loads in epilogue.
// K-loop: prefetch tile t+1 into buf^1 BEFORE computing buf (T3 minimum
// 2-phase); ONE barrier per K-step; compiler's vmcnt(0) drain at the barrier
// lands after the MFMA phase has covered the load latency.
// EPI: 1 bf16 out*(0.35+0.65*clamp(conf)); 2 gate epilogue; 3 bf16 GELU;
//      4 fp32 + residual; 5 bf16 out + per-row sum-of-squares atomics.
template <int EPI, int KC>
__global__ __launch_bounds__(256)
void mfma_gemm(const unsigned short* __restrict__ A,
               const unsigned short* __restrict__ WT,
               const float* __restrict__ bias,
               void* __restrict__ outv, int M, int N,
               const unsigned short* __restrict__ e0b,
               const float* __restrict__ e1f,
               const float* __restrict__ e2f,
               const float* __restrict__ scf) {
  __shared__ __align__(16) unsigned short As[2][128 * 64];
  __shared__ __align__(16) unsigned short Bs[2][128 * 64];
  const int tid = threadIdx.x;
  const int wid = tid >> 6, lane = tid & 63;
  const int wr = wid >> 1, wc = wid & 1;
  const int m16 = lane & 15, quad = lane >> 4;

  // XCD-chunked bijective block swizzle
  const int nwg = gridDim.x * gridDim.y;
  const int orig = blockIdx.y * gridDim.x + blockIdx.x;
  const int qq = nwg >> 3, rr = nwg & 7;
  const int xcd = orig & 7, base = orig >> 3;
  const int logical = (xcd < rr ? xcd * (qq + 1) : rr * (qq + 1) + (xcd - rr) * qq) + base;
  const int bx = logical % gridDim.x, by = logical / gridDim.x;
  const int row0 = by * 128, col0 = bx * 128;

  const floatx4 zero4 = {0.f, 0.f, 0.f, 0.f};
  floatx4 acc[4][4];
#pragma unroll
  for (int i = 0; i < 4; ++i)
#pragma unroll
    for (int j = 0; j < 4; ++j) acc[i][j] = zero4;

  // staging: slot s = wid*64 + j*256 + lane ; LDS byte = s*16 (linear);
  // r = s>>3, physical chunk pc = s&7, global chunk gc = pc ^ (r&7).
  size_t aoff[4], boff[4];
  unsigned int ldso[4];
#pragma unroll
  for (int j = 0; j < 4; ++j) {
    const int s = wid * 64 + j * 256 + lane;
    const int r = s >> 3;
    const int gc = (s & 7) ^ (r & 7);
    aoff[j] = (size_t)(row0 + r) * KC + gc * 8;
    const int br = (r & 64) + 4 * (r & 15) + ((r >> 4) & 3);   // col-permuted B row
    boff[j] = (size_t)(col0 + br) * KC + gc * 8;
    ldso[j] = (unsigned int)s * 16;
  }

  constexpr int NT = KC / 64;
  // prologue: stage tile 0 into buffer 0
#pragma unroll
  for (int j = 0; j < 4; ++j) {
    __builtin_amdgcn_global_load_lds(GPTR(A + aoff[j]), LPTR((char*)As[0] + ldso[j]), 16, 0, 0);
    __builtin_amdgcn_global_load_lds(GPTR(WT + boff[j]), LPTR((char*)Bs[0] + ldso[j]), 16, 0, 0);
  }
  __syncthreads();   // compiler drains vmcnt before s_barrier

  int cur = 0;
  for (int t = 0; t < NT; ++t) {
    if (t + 1 < NT) {
      const size_t k0n = (size_t)(t + 1) * 64;
#pragma unroll
      for (int j = 0; j < 4; ++j) {
        __builtin_amdgcn_global_load_lds(GPTR(A + aoff[j] + k0n), LPTR((char*)As[cur ^ 1] + ldso[j]), 16, 0, 0);
        __builtin_amdgcn_global_load_lds(GPTR(WT + boff[j] + k0n), LPTR((char*)Bs[cur ^ 1] + ldso[j]), 16, 0, 0);
      }
    }
#pragma unroll
    for (int kk = 0; kk < 2; ++kk) {
      const int pc = (kk * 4 + quad) ^ (m16 & 7);
      bf16x8 af[4], bfr[4];
#pragma unroll
      for (int i = 0; i < 4; ++i) {
        af[i] = *(const bf16x8*)((const char*)As[cur] + (wr * 64 + i * 16 + m16) * 128 + pc * 16);
        bfr[i] = *(const bf16x8*)((const char*)Bs[cur] + (wc * 64 + i * 16 + m16) * 128 + pc * 16);
      }
#pragma unroll
      for (int mi = 0; mi < 4; ++mi)
#pragma unroll
        for (int ni = 0; ni < 4; ++ni)
          acc[mi][ni] = __builtin_amdgcn_mfma_f32_16x16x32_bf16(af[mi], bfr[ni], acc[mi][ni], 0, 0, 0);
    }
    if (t + 1 < NT) {
      __syncthreads();   // prefetched tile landed; all reads of buf[cur] done
      cur ^= 1;
    }
  }

  float* outf = (float*)outv;
  unsigned short* outb = (unsigned short*)outv;
  const unsigned short* albf = (const unsigned short*)e1f;   // EPI==2: bf16 AO
  const int colb = col0 + wc * 64 + 4 * m16;   // 4 CONSECUTIVE output columns
  const float4 bbv = *(const float4*)(bias + colb);
  const float bb[4] = {bbv.x, bbv.y, bbv.z, bbv.w};
  const float alphav = (EPI == 2) ? scf[0] : 0.f;

#pragma unroll
  for (int mi = 0; mi < 4; ++mi) {
#pragma unroll
    for (int r = 0; r < 4; ++r) {
      const int row = row0 + wr * 64 + mi * 16 + quad * 4 + r;
      float o[4];
#pragma unroll
      for (int ni = 0; ni < 4; ++ni) o[ni] = acc[mi][ni][r] + bb[ni];
      const size_t basei = (size_t)row * N + colb;

      if (EPI == 5) {
        uint2 pk;
        pk.x = cvt2bf(o[0], o[1]);
        pk.y = cvt2bf(o[2], o[3]);
        *(uint2*)(outb + basei) = pk;
        float p = fmaf(o[0], o[0], fmaf(o[1], o[1], fmaf(o[2], o[2], o[3] * o[3])));
        p += __shfl_xor(p, 1, 64);
        p += __shfl_xor(p, 2, 64);
        p += __shfl_xor(p, 4, 64);
        p += __shfl_xor(p, 8, 64);
        if (m16 == 0) atomicAdd(const_cast<float*>(e1f) + row, p);
      } else if (EPI == 3) {
        uint2 pk;
        pk.x = cvt2bf(fast_gelu(o[0]), fast_gelu(o[1]));
        pk.y = cvt2bf(fast_gelu(o[2]), fast_gelu(o[3]));
        *(uint2*)(outb + basei) = pk;
      } else if (EPI == 1) {
        const float cm = fminf(fmaxf(e1f[row], 0.0f), 1.0f);
        const float rowscale = 0.35f + 0.65f * cm;
        uint2 pk;
        pk.x = cvt2bf(o[0] * rowscale, o[1] * rowscale);
        pk.y = cvt2bf(o[2] * rowscale, o[3] * rowscale);
        *(uint2*)(outb + basei) = pk;
      } else if (EPI == 2) {
        const float geo = fminf(fmaxf(e2f[row], 0.3f), 1.0f);
        const uint2 xpk = *(const uint2*)(e0b + basei);
        const uint2 apk = *(const uint2*)(albf + basei);
        const float xv[4] = {bf2f((unsigned short)xpk.x), bf2f((unsigned short)(xpk.x >> 16)),
                             bf2f((unsigned short)xpk.y), bf2f((unsigned short)(xpk.y >> 16))};
        const float av[4] = {bf2f((unsigned short)apk.x), bf2f((unsigned short)(apk.x >> 16)),
                             bf2f((unsigned short)apk.y), bf2f((unsigned short)(apk.y >> 16))};
        float4 ov;
        ov.x = xv[0] + alphav * fast_sigmoid(o[0]) * geo * av[0];
        ov.y = xv[1] + alphav * fast_sigmoid(o[1]) * geo * av[1];
        ov.z = xv[2] + alphav * fast_sigmoid(o[2]) * geo * av[2];
        ov.w = xv[3] + alphav * fast_sigmoid(o[3]) * geo * av[3];
        *(float4*)(outf + basei) = ov;
      } else {  // EPI == 4
        const float4 rv = *(const float4*)(e1f + basei);
        float4 ov;
        ov.x = o[0] + rv.x;
        ov.y = o[1] + rv.y;
        ov.z = o[2] + rv.z;
        ov.w = o[3] + rv.w;
        *(float4*)(outf + basei) = ov;
      }
    }
  }
}

extern "C" void kernel_launch(void* const* d_in, const int* in_sizes, int n_in,
                              void* d_out, int out_size, void* d_ws, size_t ws_size,
                              hipStream_t stream) {
  const float* visual = (const float*)d_in[0];
  const float* text   = (const float*)d_in[1];
  const float* geo    = (const float*)d_in[2];
  const float* ln1_w  = (const float*)d_in[3];
  const float* ln1_b  = (const float*)d_in[4];
  const float* wq     = (const float*)d_in[5];
  const float* bq     = (const float*)d_in[6];
  const float* wk     = (const float*)d_in[7];
  const float* bk     = (const float*)d_in[8];
  const float* wvw    = (const float*)d_in[9];
  const float* bv     = (const float*)d_in[10];
  const float* wo     = (const float*)d_in[11];
  const float* bo     = (const float*)d_in[12];
  const float* gate_w = (const float*)d_in[13];
  const float* gate_b = (const float*)d_in[14];
  const float* logit_scale = (const float*)d_in[15];
  const float* alpha  = (const float*)d_in[16];
  const float* ln2_w  = (const float*)d_in[17];
  const float* ln2_b  = (const float*)d_in[18];
  const float* ffn_w1 = (const float*)d_in[19];
  const float* ffn_b1 = (const float*)d_in[20];
  const float* ffn_w2 = (const float*)d_in[21];
  const float* ffn_b2 = (const float*)d_in[22];
  float* out = (float*)d_out;

  char* ws = (char*)d_ws;
  float* R0            = (float*)ws;                          // ALb bf16 -> GCH bf16
  float* BUF2          = (float*)(ws + 88080384);             // KV scratch -> y fp32
  unsigned short* Xb   = (unsigned short*)(ws + 155189248);   // 32 MB
  unsigned short* QNb  = (unsigned short*)(ws + 188743680);   // 32 MB q (-> AOb later)
  unsigned short* wqT  = (unsigned short*)(ws + 222298112);
  unsigned short* woT  = wqT + 262144;
  unsigned short* gateT = woT + 262144;
  unsigned short* w1T  = gateT + 262144;                      // [2048,512]
  unsigned short* w2T  = w1T + 1048576;                       // [512,2048]
  unsigned short* KHb  = w2T + 1048576;                       // [64,80,64] bf16
  float* NEGM = (float*)(ws + 230146048);                     // [8,80]
  float* CONF = (float*)(ws + 230148608);                     // [32768] conf accum
  float* SSQ  = (float*)(ws + 230279680);                     // [32768] ||q||^2

  // kv-projection scratch lives in the BUF2 region (dead after step 5/7):
  float* KV            = (float*)(ws + 88080384);             // [640,1024] fp32
  unsigned short* THi  = (unsigned short*)(ws + 88080384 + 2621440);   // [640,512]
  unsigned short* TLo  = THi + 640 * 512;
  unsigned short* WKVh = TLo + 640 * 512;                     // [1024,512]
  unsigned short* WKVl = WKVh + 1024 * 512;

  unsigned short* ALb = (unsigned short*)R0;   // aligned bf16 [32768,512]
  unsigned short* AOb = QNb;                   // q dead after fused kernel

  // weight transposes -> bf16 [N,K]
  transpose_bf16_kernel<<<dim3(16, 16), 256, 0, stream>>>(wq, wqT, 512, 512);
  transpose_bf16_kernel<<<dim3(16, 16), 256, 0, stream>>>(wo, woT, 512, 512);
  transpose_bf16_kernel<<<dim3(16, 16), 256, 0, stream>>>(gate_w, gateT, 512, 512);
  transpose_bf16_kernel<<<dim3(64, 16), 256, 0, stream>>>(ffn_w1, w1T, 512, 2048);
  transpose_bf16_kernel<<<dim3(16, 64), 256, 0, stream>>>(ffn_w2, w2T, 2048, 512);
  transpose_pair_kernel<<<dim3(16, 16), 256, 0, stream>>>(wk, WKVh, WKVl, 512, 512);
  transpose_pair_kernel<<<dim3(16, 16), 256, 0, stream>>>(wvw, WKVh + 512 * 512, WKVl + 512 * 512, 512, 512);

  // 1. x = LN1(visual) -> bf16 ; zero ss + conf accumulators
  ln_bf16_kernel<<<MTOT / 4, 256, 0, stream>>>(visual, ln1_w, ln1_b, Xb);
  zero_acc_kernel<<<128, 256, 0, stream>>>(SSQ, CONF);
  // 2. text -> hi/lo bf16 + pad mask; kv = text @ (wk|wv) via split-bf16 MFMA
  text_cvt_kernel<<<160, 256, 0, stream>>>(text, THi, TLo, NEGM);
  kv_gemm<<<dim3(8, 5), 256, 0, stream>>>(THi, TLo, WKVh, WKVl, bk, bv, KV);
  knorm_kernel<<<154, 256, 0, stream>>>(KV, KHb);
  kpad_zero_kernel<<<48, 256, 0, stream>>>(KHb, NEGM);
  // 3. q = x @ wq + bq -> bf16 QNb + per-row ss atomics (fused l2norm, part 1)
  mfma_gemm<5, 512><<<dim3(4, 256), 256, 0, stream>>>(Xb, wqT, bq, QNb, MTOT, 512,
                                                      nullptr, SSQ, nullptr, nullptr);
  // 4+5. FUSED sim -> LDS -> topk/softmax/conf/PV -> ALb bf16, CONF atomics
  sim_attn_kernel<<<dim3(32, 64), 256, 0, stream>>>(QNb, KHb, NEGM, SSQ, logit_scale,
                                                    KV + 512, ALb, CONF);
  // 6. alignedO = (aligned @ wo + bo) * (0.35+0.65*clamp(conf)) -> AOb bf16
  mfma_gemm<1, 512><<<dim3(4, 256), 256, 0, stream>>>(ALb, woT, bo, AOb, MTOT, 512,
                                                      nullptr, CONF, nullptr, nullptr);
  // 7. y = x + alpha*sigmoid(x@gate_w+gate_b)*geo*alignedO -> BUF2 (KV dead now)
  mfma_gemm<2, 512><<<dim3(4, 256), 256, 0, stream>>>(Xb, gateT, gate_b, BUF2, MTOT, 512,
                                                      Xb, (const float*)AOb, geo, alpha);
  // 8. h = LN2(y) -> Xb (bf16)
  ln_bf16_kernel<<<MTOT / 4, 256, 0, stream>>>(BUF2, ln2_w, ln2_b, Xb);
  // 9. FFN in 2 chunks of 16384 rows; GCH (bf16) overlays R0 (ALb dead)
  unsigned short* GCH = (unsigned short*)R0;
  for (int ch = 0; ch < 2; ++ch) {
    const size_t off = (size_t)ch * 16384;
    mfma_gemm<3, 512><<<dim3(16, 128), 256, 0, stream>>>(Xb + off * 512, w1T, ffn_b1, GCH,
                                                         16384, 2048,
                                                         nullptr, nullptr, nullptr, nullptr);
    mfma_gemm<4, 2048><<<dim3(4, 128), 256, 0, stream>>>(GCH, w2T, ffn_b2, out + off * 512,
                                                         16384, 512,
                                                         nullptr, BUF2 + off * 512, nullptr, nullptr);
  }
}

// Round 11
// 578.258 us; speedup vs baseline: 1.0810x; 1.0810x over previous
//
#include <hip/hip_runtime.h>
#include <hip/hip_bf16.h>
#include <math.h>

#define TT 77
#define MTOT 32768

typedef __attribute__((ext_vector_type(8))) short bf16x8;
typedef __attribute__((ext_vector_type(4))) float floatx4;

#define GPTR(p) ((const __attribute__((address_space(1))) void*)(p))
#define LPTR(p) ((__attribute__((address_space(3))) void*)(p))

__device__ __forceinline__ float wred_sum(float v) {
#pragma unroll
  for (int o = 32; o >= 1; o >>= 1) v += __shfl_xor(v, o, 64);
  return v;
}

__device__ __forceinline__ unsigned short f2bf(float f) {
  unsigned int u = __float_as_uint(f);
  unsigned int r = (u + 0x7fffu + ((u >> 16) & 1u)) >> 16;
  return (unsigned short)r;
}
__device__ __forceinline__ float bf2f(unsigned short h) {
  return __uint_as_float(((unsigned int)h) << 16);
}
// hw packed RTNE f32->bf16 (bit-identical to f2bf), 2 values in 1 inst
__device__ __forceinline__ unsigned int cvt2bf(float a, float b) {
  unsigned int r;
  asm("v_cvt_pk_bf16_f32 %0, %1, %2" : "=v"(r) : "v"(a), "v"(b));
  return r;
}

// fast erf-based GELU: Abramowitz-Stegun 7.1.26, |err| <= 1.5e-7 (way below bf16 lsb)
__device__ __forceinline__ float fast_gelu(float o) {
  const float z = fabsf(o) * 0.70710678118654752f;
  const float t = __builtin_amdgcn_rcpf(fmaf(0.3275911f, z, 1.0f));
  float p = fmaf(1.061405429f, t, -1.453152027f);
  p = fmaf(p, t, 1.421413741f);
  p = fmaf(p, t, -0.284496736f);
  p = fmaf(p, t, 0.254829592f);
  p = p * t;
  const float erfz = fmaf(-p, __expf(-z * z), 1.0f);   // erf(|o|/sqrt2)
  const float s = __builtin_copysignf(erfz, o);
  return 0.5f * o * (1.0f + s);
}

__device__ __forceinline__ float fast_sigmoid(float o) {
  return __builtin_amdgcn_rcpf(1.0f + __expf(-o));
}

// ---------------- LayerNorm over rows of 512 -> bf16 out (one wave per row) ---
__global__ __launch_bounds__(256)
void ln_bf16_kernel(const float* __restrict__ in, const float* __restrict__ gw,
                    const float* __restrict__ gb, unsigned short* __restrict__ out) {
  const int wv = threadIdx.x >> 6, lane = threadIdx.x & 63;
  const size_t row = (size_t)blockIdx.x * 4 + wv;
  const float* p = in + row * 512 + lane * 8;
  float4 a = *(const float4*)p;
  float4 b = *(const float4*)(p + 4);
  float s = a.x + a.y + a.z + a.w + b.x + b.y + b.z + b.w;
  float mu = wred_sum(s) * (1.0f / 512.0f);
  float d[8] = {a.x - mu, a.y - mu, a.z - mu, a.w - mu,
                b.x - mu, b.y - mu, b.z - mu, b.w - mu};
  float ss = 0.f;
#pragma unroll
  for (int i = 0; i < 8; ++i) ss = fmaf(d[i], d[i], ss);
  float var = wred_sum(ss) * (1.0f / 512.0f);
  float rstd = rsqrtf(var + 1e-5f);
  float4 w0 = *(const float4*)(gw + lane * 8);
  float4 w1 = *(const float4*)(gw + lane * 8 + 4);
  float4 c0 = *(const float4*)(gb + lane * 8);
  float4 c1 = *(const float4*)(gb + lane * 8 + 4);
  float o[8];
  o[0] = d[0] * rstd * w0.x + c0.x;  o[1] = d[1] * rstd * w0.y + c0.y;
  o[2] = d[2] * rstd * w0.z + c0.z;  o[3] = d[3] * rstd * w0.w + c0.w;
  o[4] = d[4] * rstd * w1.x + c1.x;  o[5] = d[5] * rstd * w1.y + c1.y;
  o[6] = d[6] * rstd * w1.z + c1.z;  o[7] = d[7] * rstd * w1.w + c1.w;
  __align__(16) unsigned short ob[8];
#pragma unroll
  for (int i = 0; i < 8; ++i) ob[i] = f2bf(o[i]);
  *(uint4*)(out + row * 512 + lane * 8) = *(const uint4*)ob;
}

// ---------------- zero the per-row ||q||^2 and conf accumulators --------------
__global__ __launch_bounds__(256)
void zero_acc_kernel(float* __restrict__ ssq, float* __restrict__ conf) {
  const int i = blockIdx.x * 256 + threadIdx.x;
  ssq[i] = 0.0f;
  conf[i] = 0.0f;
}

// ---------------- weight transpose + bf16 convert: W[K,N] -> WT[N,K] ----------
__global__ __launch_bounds__(256)
void transpose_bf16_kernel(const float* __restrict__ W, unsigned short* __restrict__ WTb,
                           int K, int N) {
  __shared__ float s[32][33];
  const int tx = threadIdx.x & 31, ty = threadIdx.x >> 5;  // ty 0..7
  const int n0 = blockIdx.x * 32, k0 = blockIdx.y * 32;
#pragma unroll
  for (int j = 0; j < 4; ++j)
    s[ty + 8 * j][tx] = W[(size_t)(k0 + ty + 8 * j) * N + n0 + tx];
  __syncthreads();
#pragma unroll
  for (int j = 0; j < 4; ++j)
    WTb[(size_t)(n0 + ty + 8 * j) * K + k0 + tx] = f2bf(s[tx][ty + 8 * j]);
}

// ---------------- pair transpose: W[K,N] -> hi/lo split bf16 WT[N,K] ----------
__global__ __launch_bounds__(256)
void transpose_pair_kernel(const float* __restrict__ W,
                           unsigned short* __restrict__ WTh,
                           unsigned short* __restrict__ WTl, int K, int N) {
  __shared__ float s[32][33];
  const int tx = threadIdx.x & 31, ty = threadIdx.x >> 5;  // ty 0..7
  const int n0 = blockIdx.x * 32, k0 = blockIdx.y * 32;
#pragma unroll
  for (int j = 0; j < 4; ++j)
    s[ty + 8 * j][tx] = W[(size_t)(k0 + ty + 8 * j) * N + n0 + tx];
  __syncthreads();
#pragma unroll
  for (int j = 0; j < 4; ++j) {
    const float a = s[tx][ty + 8 * j];
    const unsigned short hi = f2bf(a);
    WTh[(size_t)(n0 + ty + 8 * j) * K + k0 + tx] = hi;
    WTl[(size_t)(n0 + ty + 8 * j) * K + k0 + tx] = f2bf(a - bf2f(hi));
  }
}

// ---------------- text -> hi/lo bf16 split (rows 616..639 zeroed) + pad mask --
__global__ __launch_bounds__(256)
void text_cvt_kernel(const float* __restrict__ text,
                     unsigned short* __restrict__ thi,
                     unsigned short* __restrict__ tlo,
                     float* __restrict__ negm) {
  const int wv = threadIdx.x >> 6, lane = threadIdx.x & 63;
  const int row = blockIdx.x * 4 + wv;       // 0..639
  if (row >= 616) {
    const uint4 z = {0u, 0u, 0u, 0u};
    *(uint4*)(thi + (size_t)row * 512 + lane * 8) = z;
    *(uint4*)(tlo + (size_t)row * 512 + lane * 8) = z;
    return;
  }
  const float* p = text + (size_t)row * 512 + lane * 8;
  float4 a = *(const float4*)p;
  float4 b = *(const float4*)(p + 4);
  float v[8] = {a.x, a.y, a.z, a.w, b.x, b.y, b.z, b.w};
  float ab = 0.f;
#pragma unroll
  for (int i = 0; i < 8; ++i) ab += fabsf(v[i]);
  ab = wred_sum(ab);
  __align__(16) unsigned short hb[8];
  __align__(16) unsigned short lb[8];
#pragma unroll
  for (int i = 0; i < 8; ++i) {
    hb[i] = f2bf(v[i]);
    lb[i] = f2bf(v[i] - bf2f(hb[i]));
  }
  *(uint4*)(thi + (size_t)row * 512 + lane * 8) = *(const uint4*)hb;
  *(uint4*)(tlo + (size_t)row * 512 + lane * 8) = *(const uint4*)lb;
  if (lane == 0) {
    const int bb = row / 77, t = row - bb * 77;
    negm[bb * 80 + t] = (ab <= 1e-6f) ? -INFINITY : 0.0f;
  }
}

// ---------------- kv projection GEMM, split-bf16 (~fp32 exact) ----------------
__global__ __launch_bounds__(256)
void kv_gemm(const unsigned short* __restrict__ AH,
             const unsigned short* __restrict__ AL,
             const unsigned short* __restrict__ BH,
             const unsigned short* __restrict__ BL,
             const float* __restrict__ bk, const float* __restrict__ bv,
             float* __restrict__ outp) {
  const int K = 512;
  __shared__ __align__(16) unsigned short AsH[128 * 32];
  __shared__ __align__(16) unsigned short AsL[128 * 32];
  __shared__ __align__(16) unsigned short BsH[128 * 32];
  __shared__ __align__(16) unsigned short BsL[128 * 32];
  const int tid = threadIdx.x;
  const int wid = tid >> 6, lane = tid & 63;
  const int wr = wid >> 1, wc = wid & 1;
  const int m16 = lane & 15, quad = lane >> 4;
  const int row0 = blockIdx.y * 128, col0 = blockIdx.x * 128;

  const floatx4 zero4 = {0.f, 0.f, 0.f, 0.f};
  floatx4 acc[4][4];
#pragma unroll
  for (int i = 0; i < 4; ++i)
#pragma unroll
    for (int j = 0; j < 4; ++j) acc[i][j] = zero4;

  const int srow = tid >> 2;
  const int schunk = (tid & 3) ^ (srow & 3);
  const unsigned short* AgH = AH + (size_t)(row0 + srow) * K + schunk * 8;
  const unsigned short* AgL = AL + (size_t)(row0 + srow) * K + schunk * 8;
  const unsigned short* BgH = BH + (size_t)(col0 + srow) * K + schunk * 8;
  const unsigned short* BgL = BL + (size_t)(col0 + srow) * K + schunk * 8;
  char* AsHB = (char*)AsH + tid * 16;
  char* AsLB = (char*)AsL + tid * 16;
  char* BsHB = (char*)BsH + tid * 16;
  char* BsLB = (char*)BsL + tid * 16;
  const int rq = quad ^ (m16 & 3);
  const int aOfs = (wr * 64 + m16) * 32 + rq * 8;
  const int bOfs = (wc * 64 + m16) * 32 + rq * 8;

  for (int k0 = 0; k0 < K; k0 += 32) {
    __syncthreads();
    __builtin_amdgcn_global_load_lds(GPTR(AgH + k0), LPTR(AsHB), 16, 0, 0);
    __builtin_amdgcn_global_load_lds(GPTR(AgH + (size_t)64 * K + k0), LPTR(AsHB + 4096), 16, 0, 0);
    __builtin_amdgcn_global_load_lds(GPTR(AgL + k0), LPTR(AsLB), 16, 0, 0);
    __builtin_amdgcn_global_load_lds(GPTR(AgL + (size_t)64 * K + k0), LPTR(AsLB + 4096), 16, 0, 0);
    __builtin_amdgcn_global_load_lds(GPTR(BgH + k0), LPTR(BsHB), 16, 0, 0);
    __builtin_amdgcn_global_load_lds(GPTR(BgH + (size_t)64 * K + k0), LPTR(BsHB + 4096), 16, 0, 0);
    __builtin_amdgcn_global_load_lds(GPTR(BgL + k0), LPTR(BsLB), 16, 0, 0);
    __builtin_amdgcn_global_load_lds(GPTR(BgL + (size_t)64 * K + k0), LPTR(BsLB + 4096), 16, 0, 0);
    __syncthreads();
    bf16x8 afH[4], afL[4], bfH[4], bfL[4];
#pragma unroll
    for (int i = 0; i < 4; ++i) {
      afH[i] = *(const bf16x8*)(AsH + aOfs + i * 16 * 32);
      afL[i] = *(const bf16x8*)(AsL + aOfs + i * 16 * 32);
      bfH[i] = *(const bf16x8*)(BsH + bOfs + i * 16 * 32);
      bfL[i] = *(const bf16x8*)(BsL + bOfs + i * 16 * 32);
    }
#pragma unroll
    for (int mi = 0; mi < 4; ++mi)
#pragma unroll
      for (int ni = 0; ni < 4; ++ni) {
        acc[mi][ni] = __builtin_amdgcn_mfma_f32_16x16x32_bf16(afH[mi], bfH[ni], acc[mi][ni], 0, 0, 0);
        acc[mi][ni] = __builtin_amdgcn_mfma_f32_16x16x32_bf16(afH[mi], bfL[ni], acc[mi][ni], 0, 0, 0);
        acc[mi][ni] = __builtin_amdgcn_mfma_f32_16x16x32_bf16(afL[mi], bfH[ni], acc[mi][ni], 0, 0, 0);
      }
  }

  const float* bp = (col0 < 512) ? bk : bv;
  const int cbase = (col0 < 512) ? col0 : col0 - 512;
  float bb[4];
#pragma unroll
  for (int ni = 0; ni < 4; ++ni) bb[ni] = bp[cbase + wc * 64 + ni * 16 + m16];
#pragma unroll
  for (int mi = 0; mi < 4; ++mi)
#pragma unroll
    for (int r = 0; r < 4; ++r) {
      const int row = row0 + wr * 64 + mi * 16 + quad * 4 + r;
#pragma unroll
      for (int ni = 0; ni < 4; ++ni) {
        const int col = col0 + wc * 64 + ni * 16 + m16;
        outp[(size_t)row * 1024 + col] = acc[mi][ni][r] + bb[ni];
      }
    }
}

// ---------------- k rows: L2-normalize -> head-major bf16 ---------------------
__global__ __launch_bounds__(256)
void knorm_kernel(const float* __restrict__ KV,     // [640,1024], k = cols 0..511
                  unsigned short* __restrict__ khb) {  // [B,8,80,64]
  const int wv = threadIdx.x >> 6, lane = threadIdx.x & 63;
  const int row = blockIdx.x * 4 + wv;   // 0..615
  const float* p = KV + (size_t)row * 1024 + lane * 8;
  float4 a = *(const float4*)p;
  float4 b = *(const float4*)(p + 4);
  float v[8] = {a.x, a.y, a.z, a.w, b.x, b.y, b.z, b.w};
  float ss = 0.f;
#pragma unroll
  for (int i = 0; i < 8; ++i) ss = fmaf(v[i], v[i], ss);
  ss = wred_sum(ss);
  const float sc = 1.0f / fmaxf(sqrtf(ss), 1e-6f);
  const int bb = row / 77, t = row - bb * 77;
  const int c = lane * 8, h = c >> 6, d = c & 63;
  __align__(16) unsigned short ob[8];
#pragma unroll
  for (int i = 0; i < 8; ++i) ob[i] = f2bf(v[i] * sc);
  *(uint4*)(khb + (((size_t)bb * 8 + h) * 80 + t) * 64 + d) = *(const uint4*)ob;
}

// ---------------- zero the k pad rows (t = 77..79) + -inf negmask there -------
__global__ __launch_bounds__(256)
void kpad_zero_kernel(unsigned short* __restrict__ khb, float* __restrict__ negm) {
  const int i = blockIdx.x * 256 + threadIdx.x;
  const int bh = i / 192, rem = i - bh * 192;
  const int t = 77 + rem / 64, d = rem & 63;
  khb[(((size_t)bh) * 80 + t) * 64 + d] = 0;
  if (i < 24) negm[(i / 3) * 80 + 77 + (i % 3)] = -INFINITY;
}

// ---------------- FUSED: sim (MFMA) -> LDS -> topk/softmax/conf/PV ------------
// sim tile stride 84 floats (336B, 16B-aligned) so phase-2 scans via ds_read_b128.
__global__ __launch_bounds__(256)
void sim_attn_kernel(const unsigned short* __restrict__ qnb,   // [32768,512] bf16 q
                     const unsigned short* __restrict__ khb,   // [64,80,64] bf16
                     const float* __restrict__ negm,           // [8,80]
                     const float* __restrict__ ssq,            // [32768] ||q||^2
                     const float* __restrict__ logit_scale,
                     const float* __restrict__ vf,             // KV+512, stride 1024
                     unsigned short* __restrict__ alignedb,    // [32768,512] bf16
                     float* __restrict__ confacc) {            // [32768] (pre-zeroed)
  __shared__ __align__(16) char lbuf[128 * 84 * 4];   // 43008 B; unioned
  unsigned short* As = (unsigned short*)lbuf;         // [128*72] phase 1
  unsigned short* Bs = As + 128 * 72;                 // [80*72]  phase 1
  float* simt = (float*)lbuf;                         // [128][84] phase 2

  const int bh = blockIdx.y;           // b*8+h
  const int b = bh >> 3, h = bh & 7;
  const int row0 = blockIdx.x * 128;   // within 4096
  const int tid = threadIdx.x;

  {
    const int r = tid >> 1, half = tid & 1;
    const unsigned short* src = qnb + ((size_t)b * 4096 + row0 + r) * 512 + h * 64 + half * 32;
    unsigned short* dst = As + r * 72 + half * 32;
    *(uint4*)dst = *(const uint4*)src;
    *(uint4*)(dst + 8) = *(const uint4*)(src + 8);
    *(uint4*)(dst + 16) = *(const uint4*)(src + 16);
    *(uint4*)(dst + 24) = *(const uint4*)(src + 24);
  }
  if (tid < 160) {
    const int r = tid >> 1, half = tid & 1;
    const unsigned short* src = khb + ((size_t)bh * 80 + r) * 64 + half * 32;
    unsigned short* dst = Bs + r * 72 + half * 32;
    *(uint4*)dst = *(const uint4*)src;
    *(uint4*)(dst + 8) = *(const uint4*)(src + 8);
    *(uint4*)(dst + 16) = *(const uint4*)(src + 16);
    *(uint4*)(dst + 24) = *(const uint4*)(src + 24);
  }
  __syncthreads();

  const int w = tid >> 6, lane = tid & 63;
  const int m16 = lane & 15, quad = lane >> 4;
  const unsigned short* aBase = As + (w * 32 + m16) * 72 + quad * 8;
  const unsigned short* bBase = Bs + m16 * 72 + quad * 8;
  bf16x8 af[2][2], bf[5][2];
#pragma unroll
  for (int mi = 0; mi < 2; ++mi)
#pragma unroll
    for (int kk = 0; kk < 2; ++kk)
      af[mi][kk] = *(const bf16x8*)(aBase + mi * 16 * 72 + kk * 32);
#pragma unroll
  for (int ni = 0; ni < 5; ++ni)
#pragma unroll
    for (int kk = 0; kk < 2; ++kk)
      bf[ni][kk] = *(const bf16x8*)(bBase + ni * 16 * 72 + kk * 32);
  __syncthreads();   // all frag reads done before LDS reuse

  const floatx4 zero4 = {0.f, 0.f, 0.f, 0.f};
  floatx4 acc[2][5];
#pragma unroll
  for (int mi = 0; mi < 2; ++mi)
#pragma unroll
    for (int ni = 0; ni < 5; ++ni) acc[mi][ni] = zero4;
#pragma unroll
  for (int kk = 0; kk < 2; ++kk)
#pragma unroll
    for (int mi = 0; mi < 2; ++mi)
#pragma unroll
      for (int ni = 0; ni < 5; ++ni)
        acc[mi][ni] = __builtin_amdgcn_mfma_f32_16x16x32_bf16(af[mi][kk], bf[ni][kk], acc[mi][ni], 0, 0, 0);

  const float ls = fminf(fmaxf(logit_scale[0], -2.0f), 2.0f);
  const float scale = expf(ls) * 0.125f;
  float nm[5];
#pragma unroll
  for (int ni = 0; ni < 5; ++ni) nm[ni] = negm[b * 80 + ni * 16 + m16];
#pragma unroll
  for (int mi = 0; mi < 2; ++mi)
#pragma unroll
    for (int r = 0; r < 4; ++r) {
      const int lr = w * 32 + quad * 4 + mi * 16 + r;   // 0..127
      const float ssv = ssq[(size_t)b * 4096 + row0 + lr];
      const float nsc = scale / fmaxf(sqrtf(ssv), 1e-6f);
#pragma unroll
      for (int ni = 0; ni < 5; ++ni)
        simt[lr * 84 + ni * 16 + m16] = acc[mi][ni][r] * nsc + nm[ni];
    }
  __syncthreads();

  // ---- phase 2: per (row, half) top-3 + closed-form softmax + PV ----
  const int lr = tid >> 1, half = tid & 1;
  const int n = row0 + lr;
  const float* sp = simt + lr * 84;   // 16B-aligned row

  float m1 = -INFINITY, m2 = -INFINITY, m3 = -INFINITY, m4 = -INFINITY;
  int a1 = 0, a2 = 0, a3 = 0;
#pragma unroll
  for (int i = 0; i < 20; ++i) {
    const float4 q4 = ((const float4*)sp)[i];
#pragma unroll
    for (int j = 0; j < 4; ++j) {
      const float v = (j == 0) ? q4.x : (j == 1) ? q4.y : (j == 2) ? q4.z : q4.w;
      const int t = i * 4 + j;
      const bool c1 = v > m1, c2 = v > m2, c3 = v > m3, c4 = v > m4;
      m4 = c4 ? (c3 ? m3 : v) : m4;
      m3 = c3 ? (c2 ? m2 : v) : m3;
      a3 = c3 ? (c2 ? a2 : t) : a3;
      m2 = c2 ? (c1 ? m1 : v) : m2;
      a2 = c2 ? (c1 ? a1 : t) : a2;
      m1 = c1 ? v : m1;
      a1 = c1 ? t : a1;
    }
  }

  const bool dead = (m1 == -INFINITY);
  if (dead) m1 = 0.0f;
  const bool tie = (!dead) && ((m1 == m2) || (m2 == m3) || (m3 == m4));

  const float d2 = m2 - m1, d3 = m3 - m1;
  const float e2 = __expf(d2), e3 = __expf(d3);   // exp(-inf)=0
  float s0 = 1.0f + e2 + e3;
  float s1 = ((e2 > 0.f) ? e2 * d2 : 0.f) + ((e3 > 0.f) ? e3 * d3 : 0.f);
  float cntf = 1.0f + ((e2 > 0.f) ? 1.f : 0.f) + ((e3 > 0.f) ? 1.f : 0.f);

  unsigned short* op = alignedb + ((size_t)b * 4096 + n) * 512 + h * 64 + half * 32;

  if (tie) {
    s0 = 0.f; s1 = 0.f; cntf = 0.f;
    float4 acc2[8];
#pragma unroll
    for (int i = 0; i < 8; ++i) acc2[i] = (float4){0.f, 0.f, 0.f, 0.f};
    for (int t = 0; t < 80; ++t) {
      const float v = sp[t];
      if (v >= m3) {
        const float e = expf(v - m1);
        if (e > 0.f) {
          s0 += e; s1 = fmaf(e, v - m1, s1); cntf += 1.f;
          const float4* vp = (const float4*)(vf + (size_t)(b * 77 + t) * 1024 + h * 64 + half * 32);
#pragma unroll
          for (int i = 0; i < 8; ++i) {
            const float4 x = vp[i];
            acc2[i].x = fmaf(e, x.x, acc2[i].x);
            acc2[i].y = fmaf(e, x.y, acc2[i].y);
            acc2[i].z = fmaf(e, x.z, acc2[i].z);
            acc2[i].w = fmaf(e, x.w, acc2[i].w);
          }
        }
      }
    }
    const float invt = 1.0f / s0;
#pragma unroll
    for (int i = 0; i < 4; ++i) {
      const float4 lo = acc2[2 * i], hi = acc2[2 * i + 1];
      uint4 pk;
      pk.x = cvt2bf(lo.x * invt, lo.y * invt);
      pk.y = cvt2bf(lo.z * invt, lo.w * invt);
      pk.z = cvt2bf(hi.x * invt, hi.y * invt);
      pk.w = cvt2bf(hi.z * invt, hi.w * invt);
      *(uint4*)(op + i * 8) = pk;
    }
  } else {
    const float inv0 = 1.0f / s0;
    const float wA = dead ? 0.f : inv0;
    const float wB = e2 * inv0, wC = e3 * inv0;
    const float* v1p = vf + (size_t)(b * 77 + a1) * 1024 + h * 64 + half * 32;
    const float* v2p = vf + (size_t)(b * 77 + a2) * 1024 + h * 64 + half * 32;
    const float* v3p = vf + (size_t)(b * 77 + a3) * 1024 + h * 64 + half * 32;
#pragma unroll
    for (int i = 0; i < 4; ++i) {
      const float4 x0 = ((const float4*)v1p)[2 * i];
      const float4 x1 = ((const float4*)v1p)[2 * i + 1];
      const float4 y0 = ((const float4*)v2p)[2 * i];
      const float4 y1 = ((const float4*)v2p)[2 * i + 1];
      const float4 z0 = ((const float4*)v3p)[2 * i];
      const float4 z1 = ((const float4*)v3p)[2 * i + 1];
      float4 r0, r1;
      r0.x = fmaf(wC, z0.x, fmaf(wB, y0.x, wA * x0.x));
      r0.y = fmaf(wC, z0.y, fmaf(wB, y0.y, wA * x0.y));
      r0.z = fmaf(wC, z0.z, fmaf(wB, y0.z, wA * x0.z));
      r0.w = fmaf(wC, z0.w, fmaf(wB, y0.w, wA * x0.w));
      r1.x = fmaf(wC, z1.x, fmaf(wB, y1.x, wA * x1.x));
      r1.y = fmaf(wC, z1.y, fmaf(wB, y1.y, wA * x1.y));
      r1.z = fmaf(wC, z1.z, fmaf(wB, y1.z, wA * x1.z));
      r1.w = fmaf(wC, z1.w, fmaf(wB, y1.w, wA * x1.w));
      uint4 pk;
      pk.x = cvt2bf(r0.x, r0.y);
      pk.y = cvt2bf(r0.z, r0.w);
      pk.z = cvt2bf(r1.x, r1.y);
      pk.w = cvt2bf(r1.z, r1.w);
      *(uint4*)(op + i * 8) = pk;
    }
  }

  if (half == 0) {
    const float inv = 1.0f / s0;
    const float entn = (__logf(s0) - s1 * inv) + (77.0f - cntf) * 1.8420681e-7f;
    const float ent = fmaxf(entn / __logf(fmaxf(cntf, 2.0f)), 0.0f);
    float conf_h = fminf(fmaxf(inv * (1.0f - ent), 0.0f), 1.0f);
    if (dead) conf_h = 0.f;
    atomicAdd(confacc + (size_t)b * 4096 + n, conf_h * 0.125f);
  }
}

// ---------------- bf16 MFMA GEMM -----------------------------------------------
// Non-PIPE: single-buffer BK=64 (round-8 structure): [128][64] tiles, 8-chunk
//   XOR swizzle, 0 bank conflicts, 32 KB LDS.
// PIPE: 2-phase double-buffered BK=32: [2][128][32] tiles (same 32 KB LDS!),
//   4-chunk XOR swizzle; prefetch tile t+1 into buf^1 BEFORE computing buf[cur];
//   ONE barrier per K-step; occupancy preserved (the round-10 64 KB variant
//   dropped to 1 block/CU and regressed — this keeps ~4 blocks/CU).
// B staged column-permuted (LDS row holds WT row 64a+4d+c) so each lane's 4
// outputs are CONSECUTIVE columns -> vector stores/loads in epilogue.
// EPI: 1 bf16 out*(0.35+0.65*clamp(conf)); 2 gate epilogue; 3 bf16 GELU;
//      4 fp32 + residual; 5 bf16 out + per-row sum-of-squares atomics.
template <int EPI, int KC, bool PIPE = false>
__global__ __launch_bounds__(256)
void mfma_gemm(const unsigned short* __restrict__ A,
               const unsigned short* __restrict__ WT,
               const float* __restrict__ bias,
               void* __restrict__ outv, int M, int N,
               const unsigned short* __restrict__ e0b,
               const float* __restrict__ e1f,
               const float* __restrict__ e2f,
               const float* __restrict__ scf) {
  __shared__ __align__(16) unsigned short As[8192];   // 16 KB (both variants)
  __shared__ __align__(16) unsigned short Bs[8192];   // 16 KB
  const int tid = threadIdx.x;
  const int wid = tid >> 6, lane = tid & 63;
  const int wr = wid >> 1, wc = wid & 1;
  const int m16 = lane & 15, quad = lane >> 4;

  // XCD-chunked bijective block swizzle
  const int nwg = gridDim.x * gridDim.y;
  const int orig = blockIdx.y * gridDim.x + blockIdx.x;
  const int qq = nwg >> 3, rr = nwg & 7;
  const int xcd = orig & 7, base = orig >> 3;
  const int logical = (xcd < rr ? xcd * (qq + 1) : rr * (qq + 1) + (xcd - rr) * qq) + base;
  const int bx = logical % gridDim.x, by = logical / gridDim.x;
  const int row0 = by * 128, col0 = bx * 128;

  const floatx4 zero4 = {0.f, 0.f, 0.f, 0.f};
  floatx4 acc[4][4];
#pragma unroll
  for (int i = 0; i < 4; ++i)
#pragma unroll
    for (int j = 0; j < 4; ++j) acc[i][j] = zero4;

  if constexpr (!PIPE) {
    // ---- single-buffer BK=64, 8-chunk XOR swizzle (round-8) ----
    size_t aoff[4], boff[4];
    unsigned int ldso[4];
#pragma unroll
    for (int j = 0; j < 4; ++j) {
      const int s = wid * 64 + j * 256 + lane;
      const int r = s >> 3;
      const int gc = (s & 7) ^ (r & 7);
      aoff[j] = (size_t)(row0 + r) * KC + gc * 8;
      const int br = (r & 64) + 4 * (r & 15) + ((r >> 4) & 3);   // col-permuted B row
      boff[j] = (size_t)(col0 + br) * KC + gc * 8;
      ldso[j] = (unsigned int)s * 16;
    }
    for (int k0 = 0; k0 < KC; k0 += 64) {
      __syncthreads();
#pragma unroll
      for (int j = 0; j < 4; ++j) {
        __builtin_amdgcn_global_load_lds(GPTR(A + aoff[j] + k0), LPTR((char*)As + ldso[j]), 16, 0, 0);
        __builtin_amdgcn_global_load_lds(GPTR(WT + boff[j] + k0), LPTR((char*)Bs + ldso[j]), 16, 0, 0);
      }
      __syncthreads();
#pragma unroll
      for (int kk = 0; kk < 2; ++kk) {
        const int pc = (kk * 4 + quad) ^ (m16 & 7);
        bf16x8 af[4], bfr[4];
#pragma unroll
        for (int i = 0; i < 4; ++i) {
          af[i] = *(const bf16x8*)((const char*)As + (wr * 64 + i * 16 + m16) * 128 + pc * 16);
          bfr[i] = *(const bf16x8*)((const char*)Bs + (wc * 64 + i * 16 + m16) * 128 + pc * 16);
        }
#pragma unroll
        for (int mi = 0; mi < 4; ++mi)
#pragma unroll
          for (int ni = 0; ni < 4; ++ni)
            acc[mi][ni] = __builtin_amdgcn_mfma_f32_16x16x32_bf16(af[mi], bfr[ni], acc[mi][ni], 0, 0, 0);
      }
    }
  } else {
    // ---- double-buffer BK=32 2-phase pipeline, 4-chunk XOR swizzle ----
    // buffer b at byte offset b*8192 in As/Bs; tile = 128 rows x 64 B.
    size_t aoff[2], boff[2];
    unsigned int ldso[2];
#pragma unroll
    for (int j = 0; j < 2; ++j) {
      const int s = j * 256 + tid;     // 0..511
      const int r = s >> 2;            // row 0..127
      const int gc = (s & 3) ^ (r & 3);
      aoff[j] = (size_t)(row0 + r) * KC + gc * 8;
      const int br = (r & 64) + 4 * (r & 15) + ((r >> 4) & 3);   // col-permuted B row
      boff[j] = (size_t)(col0 + br) * KC + gc * 8;
      ldso[j] = (unsigned int)s * 16;
    }
    const int rq = quad ^ (m16 & 3);
    const int NT = KC / 32;
    // prologue: stage tile 0 into buffer 0
#pragma unroll
    for (int j = 0; j < 2; ++j) {
      __builtin_amdgcn_global_load_lds(GPTR(A + aoff[j]), LPTR((char*)As + ldso[j]), 16, 0, 0);
      __builtin_amdgcn_global_load_lds(GPTR(WT + boff[j]), LPTR((char*)Bs + ldso[j]), 16, 0, 0);
    }
    __syncthreads();
    int cur = 0;
    for (int t = 0; t < NT; ++t) {
      if (t + 1 < NT) {
        const size_t k0n = (size_t)(t + 1) * 32;
        const unsigned int bofs = (unsigned int)(cur ^ 1) * 8192;
#pragma unroll
        for (int j = 0; j < 2; ++j) {
          __builtin_amdgcn_global_load_lds(GPTR(A + aoff[j] + k0n), LPTR((char*)As + bofs + ldso[j]), 16, 0, 0);
          __builtin_amdgcn_global_load_lds(GPTR(WT + boff[j] + k0n), LPTR((char*)Bs + bofs + ldso[j]), 16, 0, 0);
        }
      }
      {
        const unsigned int cofs = (unsigned int)cur * 8192;
        bf16x8 af[4], bfr[4];
#pragma unroll
        for (int i = 0; i < 4; ++i) {
          af[i] = *(const bf16x8*)((const char*)As + cofs + (wr * 64 + i * 16 + m16) * 64 + rq * 16);
          bfr[i] = *(const bf16x8*)((const char*)Bs + cofs + (wc * 64 + i * 16 + m16) * 64 + rq * 16);
        }
#pragma unroll
        for (int mi = 0; mi < 4; ++mi)
#pragma unroll
          for (int ni = 0; ni < 4; ++ni)
            acc[mi][ni] = __builtin_amdgcn_mfma_f32_16x16x32_bf16(af[mi], bfr[ni], acc[mi][ni], 0, 0, 0);
      }
      if (t + 1 < NT) {
        __syncthreads();   // prefetched tile landed; all reads of buf[cur] done
        cur ^= 1;
      }
    }
  }

  float* outf = (float*)outv;
  unsigned short* outb = (unsigned short*)outv;
  const unsigned short* albf = (const unsigned short*)e1f;   // EPI==2: bf16 AO
  const int colb = col0 + wc * 64 + 4 * m16;   // 4 CONSECUTIVE output columns
  const float4 bbv = *(const float4*)(bias + colb);
  const float bb[4] = {bbv.x, bbv.y, bbv.z, bbv.w};
  const float alphav = (EPI == 2) ? scf[0] : 0.f;

#pragma unroll
  for (int mi = 0; mi < 4; ++mi) {
#pragma unroll
    for (int r = 0; r < 4; ++r) {
      const int row = row0 + wr * 64 + mi * 16 + quad * 4 + r;
      float o[4];
#pragma unroll
      for (int ni = 0; ni < 4; ++ni) o[ni] = acc[mi][ni][r] + bb[ni];
      const size_t basei = (size_t)row * N + colb;

      if (EPI == 5) {
        uint2 pk;
        pk.x = cvt2bf(o[0], o[1]);
        pk.y = cvt2bf(o[2], o[3]);
        *(uint2*)(outb + basei) = pk;
        float p = fmaf(o[0], o[0], fmaf(o[1], o[1], fmaf(o[2], o[2], o[3] * o[3])));
        p += __shfl_xor(p, 1, 64);
        p += __shfl_xor(p, 2, 64);
        p += __shfl_xor(p, 4, 64);
        p += __shfl_xor(p, 8, 64);
        if (m16 == 0) atomicAdd(const_cast<float*>(e1f) + row, p);
      } else if (EPI == 3) {
        uint2 pk;
        pk.x = cvt2bf(fast_gelu(o[0]), fast_gelu(o[1]));
        pk.y = cvt2bf(fast_gelu(o[2]), fast_gelu(o[3]));
        *(uint2*)(outb + basei) = pk;
      } else if (EPI == 1) {
        const float cm = fminf(fmaxf(e1f[row], 0.0f), 1.0f);
        const float rowscale = 0.35f + 0.65f * cm;
        uint2 pk;
        pk.x = cvt2bf(o[0] * rowscale, o[1] * rowscale);
        pk.y = cvt2bf(o[2] * rowscale, o[3] * rowscale);
        *(uint2*)(outb + basei) = pk;
      } else if (EPI == 2) {
        const float geo = fminf(fmaxf(e2f[row], 0.3f), 1.0f);
        const uint2 xpk = *(const uint2*)(e0b + basei);
        const uint2 apk = *(const uint2*)(albf + basei);
        const float xv[4] = {bf2f((unsigned short)xpk.x), bf2f((unsigned short)(xpk.x >> 16)),
                             bf2f((unsigned short)xpk.y), bf2f((unsigned short)(xpk.y >> 16))};
        const float av[4] = {bf2f((unsigned short)apk.x), bf2f((unsigned short)(apk.x >> 16)),
                             bf2f((unsigned short)apk.y), bf2f((unsigned short)(apk.y >> 16))};
        float4 ov;
        ov.x = xv[0] + alphav * fast_sigmoid(o[0]) * geo * av[0];
        ov.y = xv[1] + alphav * fast_sigmoid(o[1]) * geo * av[1];
        ov.z = xv[2] + alphav * fast_sigmoid(o[2]) * geo * av[2];
        ov.w = xv[3] + alphav * fast_sigmoid(o[3]) * geo * av[3];
        *(float4*)(outf + basei) = ov;
      } else {  // EPI == 4
        const float4 rv = *(const float4*)(e1f + basei);
        float4 ov;
        ov.x = o[0] + rv.x;
        ov.y = o[1] + rv.y;
        ov.z = o[2] + rv.z;
        ov.w = o[3] + rv.w;
        *(float4*)(outf + basei) = ov;
      }
    }
  }
}

extern "C" void kernel_launch(void* const* d_in, const int* in_sizes, int n_in,
                              void* d_out, int out_size, void* d_ws, size_t ws_size,
                              hipStream_t stream) {
  const float* visual = (const float*)d_in[0];
  const float* text   = (const float*)d_in[1];
  const float* geo    = (const float*)d_in[2];
  const float* ln1_w  = (const float*)d_in[3];
  const float* ln1_b  = (const float*)d_in[4];
  const float* wq     = (const float*)d_in[5];
  const float* bq     = (const float*)d_in[6];
  const float* wk     = (const float*)d_in[7];
  const float* bk     = (const float*)d_in[8];
  const float* wvw    = (const float*)d_in[9];
  const float* bv     = (const float*)d_in[10];
  const float* wo     = (const float*)d_in[11];
  const float* bo     = (const float*)d_in[12];
  const float* gate_w = (const float*)d_in[13];
  const float* gate_b = (const float*)d_in[14];
  const float* logit_scale = (const float*)d_in[15];
  const float* alpha  = (const float*)d_in[16];
  const float* ln2_w  = (const float*)d_in[17];
  const float* ln2_b  = (const float*)d_in[18];
  const float* ffn_w1 = (const float*)d_in[19];
  const float* ffn_b1 = (const float*)d_in[20];
  const float* ffn_w2 = (const float*)d_in[21];
  const float* ffn_b2 = (const float*)d_in[22];
  float* out = (float*)d_out;

  char* ws = (char*)d_ws;
  float* R0            = (float*)ws;                          // ALb bf16 -> GCH bf16
  float* BUF2          = (float*)(ws + 88080384);             // KV scratch -> y fp32
  unsigned short* Xb   = (unsigned short*)(ws + 155189248);   // 32 MB
  unsigned short* QNb  = (unsigned short*)(ws + 188743680);   // 32 MB q (-> AOb later)
  unsigned short* wqT  = (unsigned short*)(ws + 222298112);
  unsigned short* woT  = wqT + 262144;
  unsigned short* gateT = woT + 262144;
  unsigned short* w1T  = gateT + 262144;                      // [2048,512]
  unsigned short* w2T  = w1T + 1048576;                       // [512,2048]
  unsigned short* KHb  = w2T + 1048576;                       // [64,80,64] bf16
  float* NEGM = (float*)(ws + 230146048);                     // [8,80]
  float* CONF = (float*)(ws + 230148608);                     // [32768] conf accum
  float* SSQ  = (float*)(ws + 230279680);                     // [32768] ||q||^2

  // kv-projection scratch lives in the BUF2 region (dead after step 5/7):
  float* KV            = (float*)(ws + 88080384);             // [640,1024] fp32
  unsigned short* THi  = (unsigned short*)(ws + 88080384 + 2621440);   // [640,512]
  unsigned short* TLo  = THi + 640 * 512;
  unsigned short* WKVh = TLo + 640 * 512;                     // [1024,512]
  unsigned short* WKVl = WKVh + 1024 * 512;

  unsigned short* ALb = (unsigned short*)R0;   // aligned bf16 [32768,512]
  unsigned short* AOb = QNb;                   // q dead after fused kernel

  // weight transposes -> bf16 [N,K]
  transpose_bf16_kernel<<<dim3(16, 16), 256, 0, stream>>>(wq, wqT, 512, 512);
  transpose_bf16_kernel<<<dim3(16, 16), 256, 0, stream>>>(wo, woT, 512, 512);
  transpose_bf16_kernel<<<dim3(16, 16), 256, 0, stream>>>(gate_w, gateT, 512, 512);
  transpose_bf16_kernel<<<dim3(64, 16), 256, 0, stream>>>(ffn_w1, w1T, 512, 2048);
  transpose_bf16_kernel<<<dim3(16, 64), 256, 0, stream>>>(ffn_w2, w2T, 2048, 512);
  transpose_pair_kernel<<<dim3(16, 16), 256, 0, stream>>>(wk, WKVh, WKVl, 512, 512);
  transpose_pair_kernel<<<dim3(16, 16), 256, 0, stream>>>(wvw, WKVh + 512 * 512, WKVl + 512 * 512, 512, 512);

  // 1. x = LN1(visual) -> bf16 ; zero ss + conf accumulators
  ln_bf16_kernel<<<MTOT / 4, 256, 0, stream>>>(visual, ln1_w, ln1_b, Xb);
  zero_acc_kernel<<<128, 256, 0, stream>>>(SSQ, CONF);
  // 2. text -> hi/lo bf16 + pad mask; kv = text @ (wk|wv) via split-bf16 MFMA
  text_cvt_kernel<<<160, 256, 0, stream>>>(text, THi, TLo, NEGM);
  kv_gemm<<<dim3(8, 5), 256, 0, stream>>>(THi, TLo, WKVh, WKVl, bk, bv, KV);
  knorm_kernel<<<154, 256, 0, stream>>>(KV, KHb);
  kpad_zero_kernel<<<48, 256, 0, stream>>>(KHb, NEGM);
  // 3. q = x @ wq + bq -> bf16 QNb + per-row ss atomics (fused l2norm, part 1)
  mfma_gemm<5, 512><<<dim3(4, 256), 256, 0, stream>>>(Xb, wqT, bq, QNb, MTOT, 512,
                                                      nullptr, SSQ, nullptr, nullptr);
  // 4+5. FUSED sim -> LDS -> topk/softmax/conf/PV -> ALb bf16, CONF atomics
  sim_attn_kernel<<<dim3(32, 64), 256, 0, stream>>>(QNb, KHb, NEGM, SSQ, logit_scale,
                                                    KV + 512, ALb, CONF);
  // 6. alignedO = (aligned @ wo + bo) * (0.35+0.65*clamp(conf)) -> AOb bf16
  mfma_gemm<1, 512><<<dim3(4, 256), 256, 0, stream>>>(ALb, woT, bo, AOb, MTOT, 512,
                                                      nullptr, CONF, nullptr, nullptr);
  // 7. y = x + alpha*sigmoid(x@gate_w+gate_b)*geo*alignedO -> BUF2 (KV dead now)
  mfma_gemm<2, 512><<<dim3(4, 256), 256, 0, stream>>>(Xb, gateT, gate_b, BUF2, MTOT, 512,
                                                      Xb, (const float*)AOb, geo, alpha);
  // 8. h = LN2(y) -> Xb (bf16)
  ln_bf16_kernel<<<MTOT / 4, 256, 0, stream>>>(BUF2, ln2_w, ln2_b, Xb);
  // 9. FFN in 2 chunks of 16384 rows; GCH (bf16) overlays R0 (ALb dead)
  //    FFN1 uses the BK=32 2-phase pipelined variant (PIPE=true).
  unsigned short* GCH = (unsigned short*)R0;
  for (int ch = 0; ch < 2; ++ch) {
    const size_t off = (size_t)ch * 16384;
    mfma_gemm<3, 512, true><<<dim3(16, 128), 256, 0, stream>>>(Xb + off * 512, w1T, ffn_b1, GCH,
                                                               16384, 2048,
                                                               nullptr, nullptr, nullptr, nullptr);
    mfma_gemm<4, 2048><<<dim3(4, 128), 256, 0, stream>>>(GCH, w2T, ffn_b2, out + off * 512,
                                                         16384, 512,
                                                         nullptr, BUF2 + off * 512, nullptr, nullptr);
  }
}

// Round 13
// 559.597 us; speedup vs baseline: 1.1170x; 1.0333x over previous
//
#include <hip/hip_runtime.h>
#include <hip/hip_bf16.h>
#include <math.h>

#define TT 77
#define MTOT 32768

typedef __attribute__((ext_vector_type(8))) short bf16x8;
typedef __attribute__((ext_vector_type(4))) float floatx4;

#define GPTR(p) ((const __attribute__((address_space(1))) void*)(p))
#define LPTR(p) ((__attribute__((address_space(3))) void*)(p))

__device__ __forceinline__ float wred_sum(float v) {
#pragma unroll
  for (int o = 32; o >= 1; o >>= 1) v += __shfl_xor(v, o, 64);
  return v;
}

__device__ __forceinline__ unsigned short f2bf(float f) {
  unsigned int u = __float_as_uint(f);
  unsigned int r = (u + 0x7fffu + ((u >> 16) & 1u)) >> 16;
  return (unsigned short)r;
}
__device__ __forceinline__ float bf2f(unsigned short h) {
  return __uint_as_float(((unsigned int)h) << 16);
}
// hw packed RTNE f32->bf16 (bit-identical to f2bf), 2 values in 1 inst
__device__ __forceinline__ unsigned int cvt2bf(float a, float b) {
  unsigned int r;
  asm("v_cvt_pk_bf16_f32 %0, %1, %2" : "=v"(r) : "v"(a), "v"(b));
  return r;
}

// fast erf-based GELU: Abramowitz-Stegun 7.1.26, |err| <= 1.5e-7 (way below bf16 lsb)
__device__ __forceinline__ float fast_gelu(float o) {
  const float z = fabsf(o) * 0.70710678118654752f;
  const float t = __builtin_amdgcn_rcpf(fmaf(0.3275911f, z, 1.0f));
  float p = fmaf(1.061405429f, t, -1.453152027f);
  p = fmaf(p, t, 1.421413741f);
  p = fmaf(p, t, -0.284496736f);
  p = fmaf(p, t, 0.254829592f);
  p = p * t;
  const float erfz = fmaf(-p, __expf(-z * z), 1.0f);   // erf(|o|/sqrt2)
  const float s = __builtin_copysignf(erfz, o);
  return 0.5f * o * (1.0f + s);
}

__device__ __forceinline__ float fast_sigmoid(float o) {
  return __builtin_amdgcn_rcpf(1.0f + __expf(-o));
}

// ---------------- LayerNorm over rows of 512 -> bf16 out (one wave per row) ---
__global__ __launch_bounds__(256)
void ln_bf16_kernel(const float* __restrict__ in, const float* __restrict__ gw,
                    const float* __restrict__ gb, unsigned short* __restrict__ out) {
  const int wv = threadIdx.x >> 6, lane = threadIdx.x & 63;
  const size_t row = (size_t)blockIdx.x * 4 + wv;
  const float* p = in + row * 512 + lane * 8;
  float4 a = *(const float4*)p;
  float4 b = *(const float4*)(p + 4);
  float s = a.x + a.y + a.z + a.w + b.x + b.y + b.z + b.w;
  float mu = wred_sum(s) * (1.0f / 512.0f);
  float d[8] = {a.x - mu, a.y - mu, a.z - mu, a.w - mu,
                b.x - mu, b.y - mu, b.z - mu, b.w - mu};
  float ss = 0.f;
#pragma unroll
  for (int i = 0; i < 8; ++i) ss = fmaf(d[i], d[i], ss);
  float var = wred_sum(ss) * (1.0f / 512.0f);
  float rstd = rsqrtf(var + 1e-5f);
  float4 w0 = *(const float4*)(gw + lane * 8);
  float4 w1 = *(const float4*)(gw + lane * 8 + 4);
  float4 c0 = *(const float4*)(gb + lane * 8);
  float4 c1 = *(const float4*)(gb + lane * 8 + 4);
  float o[8];
  o[0] = d[0] * rstd * w0.x + c0.x;  o[1] = d[1] * rstd * w0.y + c0.y;
  o[2] = d[2] * rstd * w0.z + c0.z;  o[3] = d[3] * rstd * w0.w + c0.w;
  o[4] = d[4] * rstd * w1.x + c1.x;  o[5] = d[5] * rstd * w1.y + c1.y;
  o[6] = d[6] * rstd * w1.z + c1.z;  o[7] = d[7] * rstd * w1.w + c1.w;
  __align__(16) unsigned short ob[8];
#pragma unroll
  for (int i = 0; i < 8; ++i) ob[i] = f2bf(o[i]);
  *(uint4*)(out + row * 512 + lane * 8) = *(const uint4*)ob;
}

// ---------------- zero the per-row ||q||^2 and conf accumulators --------------
__global__ __launch_bounds__(256)
void zero_acc_kernel(float* __restrict__ ssq, float* __restrict__ conf) {
  const int i = blockIdx.x * 256 + threadIdx.x;
  ssq[i] = 0.0f;
  conf[i] = 0.0f;
}

// ---------------- weight transpose + bf16 convert: W[K,N] -> WT[N,K] ----------
__global__ __launch_bounds__(256)
void transpose_bf16_kernel(const float* __restrict__ W, unsigned short* __restrict__ WTb,
                           int K, int N) {
  __shared__ float s[32][33];
  const int tx = threadIdx.x & 31, ty = threadIdx.x >> 5;  // ty 0..7
  const int n0 = blockIdx.x * 32, k0 = blockIdx.y * 32;
#pragma unroll
  for (int j = 0; j < 4; ++j)
    s[ty + 8 * j][tx] = W[(size_t)(k0 + ty + 8 * j) * N + n0 + tx];
  __syncthreads();
#pragma unroll
  for (int j = 0; j < 4; ++j)
    WTb[(size_t)(n0 + ty + 8 * j) * K + k0 + tx] = f2bf(s[tx][ty + 8 * j]);
}

// ---------------- pair transpose: W[K,N] -> hi/lo split bf16 WT[N,K] ----------
__global__ __launch_bounds__(256)
void transpose_pair_kernel(const float* __restrict__ W,
                           unsigned short* __restrict__ WTh,
                           unsigned short* __restrict__ WTl, int K, int N) {
  __shared__ float s[32][33];
  const int tx = threadIdx.x & 31, ty = threadIdx.x >> 5;  // ty 0..7
  const int n0 = blockIdx.x * 32, k0 = blockIdx.y * 32;
#pragma unroll
  for (int j = 0; j < 4; ++j)
    s[ty + 8 * j][tx] = W[(size_t)(k0 + ty + 8 * j) * N + n0 + tx];
  __syncthreads();
#pragma unroll
  for (int j = 0; j < 4; ++j) {
    const float a = s[tx][ty + 8 * j];
    const unsigned short hi = f2bf(a);
    WTh[(size_t)(n0 + ty + 8 * j) * K + k0 + tx] = hi;
    WTl[(size_t)(n0 + ty + 8 * j) * K + k0 + tx] = f2bf(a - bf2f(hi));
  }
}

// ---------------- text -> hi/lo bf16 split (rows 616..639 zeroed) + pad mask --
__global__ __launch_bounds__(256)
void text_cvt_kernel(const float* __restrict__ text,
                     unsigned short* __restrict__ thi,
                     unsigned short* __restrict__ tlo,
                     float* __restrict__ negm) {
  const int wv = threadIdx.x >> 6, lane = threadIdx.x & 63;
  const int row = blockIdx.x * 4 + wv;       // 0..639
  if (row >= 616) {
    const uint4 z = {0u, 0u, 0u, 0u};
    *(uint4*)(thi + (size_t)row * 512 + lane * 8) = z;
    *(uint4*)(tlo + (size_t)row * 512 + lane * 8) = z;
    return;
  }
  const float* p = text + (size_t)row * 512 + lane * 8;
  float4 a = *(const float4*)p;
  float4 b = *(const float4*)(p + 4);
  float v[8] = {a.x, a.y, a.z, a.w, b.x, b.y, b.z, b.w};
  float ab = 0.f;
#pragma unroll
  for (int i = 0; i < 8; ++i) ab += fabsf(v[i]);
  ab = wred_sum(ab);
  __align__(16) unsigned short hb[8];
  __align__(16) unsigned short lb[8];
#pragma unroll
  for (int i = 0; i < 8; ++i) {
    hb[i] = f2bf(v[i]);
    lb[i] = f2bf(v[i] - bf2f(hb[i]));
  }
  *(uint4*)(thi + (size_t)row * 512 + lane * 8) = *(const uint4*)hb;
  *(uint4*)(tlo + (size_t)row * 512 + lane * 8) = *(const uint4*)lb;
  if (lane == 0) {
    const int bb = row / 77, t = row - bb * 77;
    negm[bb * 80 + t] = (ab <= 1e-6f) ? -INFINITY : 0.0f;
  }
}

// ---------------- kv projection GEMM, split-bf16 (~fp32 exact) ----------------
__global__ __launch_bounds__(256)
void kv_gemm(const unsigned short* __restrict__ AH,
             const unsigned short* __restrict__ AL,
             const unsigned short* __restrict__ BH,
             const unsigned short* __restrict__ BL,
             const float* __restrict__ bk, const float* __restrict__ bv,
             float* __restrict__ outp) {
  const int K = 512;
  __shared__ __align__(16) unsigned short AsH[128 * 32];
  __shared__ __align__(16) unsigned short AsL[128 * 32];
  __shared__ __align__(16) unsigned short BsH[128 * 32];
  __shared__ __align__(16) unsigned short BsL[128 * 32];
  const int tid = threadIdx.x;
  const int wid = tid >> 6, lane = tid & 63;
  const int wr = wid >> 1, wc = wid & 1;
  const int m16 = lane & 15, quad = lane >> 4;
  const int row0 = blockIdx.y * 128, col0 = blockIdx.x * 128;

  const floatx4 zero4 = {0.f, 0.f, 0.f, 0.f};
  floatx4 acc[4][4];
#pragma unroll
  for (int i = 0; i < 4; ++i)
#pragma unroll
    for (int j = 0; j < 4; ++j) acc[i][j] = zero4;

  const int srow = tid >> 2;
  const int schunk = (tid & 3) ^ (srow & 3);
  const unsigned short* AgH = AH + (size_t)(row0 + srow) * K + schunk * 8;
  const unsigned short* AgL = AL + (size_t)(row0 + srow) * K + schunk * 8;
  const unsigned short* BgH = BH + (size_t)(col0 + srow) * K + schunk * 8;
  const unsigned short* BgL = BL + (size_t)(col0 + srow) * K + schunk * 8;
  char* AsHB = (char*)AsH + tid * 16;
  char* AsLB = (char*)AsL + tid * 16;
  char* BsHB = (char*)BsH + tid * 16;
  char* BsLB = (char*)BsL + tid * 16;
  const int rq = quad ^ (m16 & 3);
  const int aOfs = (wr * 64 + m16) * 32 + rq * 8;
  const int bOfs = (wc * 64 + m16) * 32 + rq * 8;

  for (int k0 = 0; k0 < K; k0 += 32) {
    __syncthreads();
    __builtin_amdgcn_global_load_lds(GPTR(AgH + k0), LPTR(AsHB), 16, 0, 0);
    __builtin_amdgcn_global_load_lds(GPTR(AgH + (size_t)64 * K + k0), LPTR(AsHB + 4096), 16, 0, 0);
    __builtin_amdgcn_global_load_lds(GPTR(AgL + k0), LPTR(AsLB), 16, 0, 0);
    __builtin_amdgcn_global_load_lds(GPTR(AgL + (size_t)64 * K + k0), LPTR(AsLB + 4096), 16, 0, 0);
    __builtin_amdgcn_global_load_lds(GPTR(BgH + k0), LPTR(BsHB), 16, 0, 0);
    __builtin_amdgcn_global_load_lds(GPTR(BgH + (size_t)64 * K + k0), LPTR(BsHB + 4096), 16, 0, 0);
    __builtin_amdgcn_global_load_lds(GPTR(BgL + k0), LPTR(BsLB), 16, 0, 0);
    __builtin_amdgcn_global_load_lds(GPTR(BgL + (size_t)64 * K + k0), LPTR(BsLB + 4096), 16, 0, 0);
    __syncthreads();
    bf16x8 afH[4], afL[4], bfH[4], bfL[4];
#pragma unroll
    for (int i = 0; i < 4; ++i) {
      afH[i] = *(const bf16x8*)(AsH + aOfs + i * 16 * 32);
      afL[i] = *(const bf16x8*)(AsL + aOfs + i * 16 * 32);
      bfH[i] = *(const bf16x8*)(BsH + bOfs + i * 16 * 32);
      bfL[i] = *(const bf16x8*)(BsL + bOfs + i * 16 * 32);
    }
#pragma unroll
    for (int mi = 0; mi < 4; ++mi)
#pragma unroll
      for (int ni = 0; ni < 4; ++ni) {
        acc[mi][ni] = __builtin_amdgcn_mfma_f32_16x16x32_bf16(afH[mi], bfH[ni], acc[mi][ni], 0, 0, 0);
        acc[mi][ni] = __builtin_amdgcn_mfma_f32_16x16x32_bf16(afH[mi], bfL[ni], acc[mi][ni], 0, 0, 0);
        acc[mi][ni] = __builtin_amdgcn_mfma_f32_16x16x32_bf16(afL[mi], bfH[ni], acc[mi][ni], 0, 0, 0);
      }
  }

  const float* bp = (col0 < 512) ? bk : bv;
  const int cbase = (col0 < 512) ? col0 : col0 - 512;
  float bb[4];
#pragma unroll
  for (int ni = 0; ni < 4; ++ni) bb[ni] = bp[cbase + wc * 64 + ni * 16 + m16];
#pragma unroll
  for (int mi = 0; mi < 4; ++mi)
#pragma unroll
    for (int r = 0; r < 4; ++r) {
      const int row = row0 + wr * 64 + mi * 16 + quad * 4 + r;
#pragma unroll
      for (int ni = 0; ni < 4; ++ni) {
        const int col = col0 + wc * 64 + ni * 16 + m16;
        outp[(size_t)row * 1024 + col] = acc[mi][ni][r] + bb[ni];
      }
    }
}

// ---------------- k rows: L2-normalize -> head-major bf16 ---------------------
__global__ __launch_bounds__(256)
void knorm_kernel(const float* __restrict__ KV,     // [640,1024], k = cols 0..511
                  unsigned short* __restrict__ khb) {  // [B,8,80,64]
  const int wv = threadIdx.x >> 6, lane = threadIdx.x & 63;
  const int row = blockIdx.x * 4 + wv;   // 0..615
  const float* p = KV + (size_t)row * 1024 + lane * 8;
  float4 a = *(const float4*)p;
  float4 b = *(const float4*)(p + 4);
  float v[8] = {a.x, a.y, a.z, a.w, b.x, b.y, b.z, b.w};
  float ss = 0.f;
#pragma unroll
  for (int i = 0; i < 8; ++i) ss = fmaf(v[i], v[i], ss);
  ss = wred_sum(ss);
  const float sc = 1.0f / fmaxf(sqrtf(ss), 1e-6f);
  const int bb = row / 77, t = row - bb * 77;
  const int c = lane * 8, h = c >> 6, d = c & 63;
  __align__(16) unsigned short ob[8];
#pragma unroll
  for (int i = 0; i < 8; ++i) ob[i] = f2bf(v[i] * sc);
  *(uint4*)(khb + (((size_t)bb * 8 + h) * 80 + t) * 64 + d) = *(const uint4*)ob;
}

// ---------------- zero the k pad rows (t = 77..79) + -inf negmask there -------
__global__ __launch_bounds__(256)
void kpad_zero_kernel(unsigned short* __restrict__ khb, float* __restrict__ negm) {
  const int i = blockIdx.x * 256 + threadIdx.x;
  const int bh = i / 192, rem = i - bh * 192;
  const int t = 77 + rem / 64, d = rem & 63;
  khb[(((size_t)bh) * 80 + t) * 64 + d] = 0;
  if (i < 24) negm[(i / 3) * 80 + 77 + (i % 3)] = -INFINITY;
}

// ---------------- FUSED: sim (MFMA) -> LDS -> topk/softmax/conf/PV ------------
// sim tile stride 81 floats (coprime with 32 banks -> conflict-free phase-2).
// Phase 2: the 80-elem top-3 scan is SPLIT across the row's two half-threads
// (40 each), then merged via a static 8-candidate insertion (exact semantics).
__global__ __launch_bounds__(256)
void sim_attn_kernel(const unsigned short* __restrict__ qnb,   // [32768,512] bf16 q
                     const unsigned short* __restrict__ khb,   // [64,80,64] bf16
                     const float* __restrict__ negm,           // [8,80]
                     const float* __restrict__ ssq,            // [32768] ||q||^2
                     const float* __restrict__ logit_scale,
                     const float* __restrict__ vf,             // KV+512, stride 1024
                     unsigned short* __restrict__ alignedb,    // [32768,512] bf16
                     float* __restrict__ confacc) {            // [32768] (pre-zeroed)
  __shared__ __align__(16) char lbuf[128 * 81 * 4];   // 41472 B; unioned
  unsigned short* As = (unsigned short*)lbuf;         // [128*72] phase 1
  unsigned short* Bs = As + 128 * 72;                 // [80*72]  phase 1
  float* simt = (float*)lbuf;                         // [128][81] phase 2

  const int bh = blockIdx.y;           // b*8+h
  const int b = bh >> 3, h = bh & 7;
  const int row0 = blockIdx.x * 128;   // within 4096
  const int tid = threadIdx.x;

  {
    const int r = tid >> 1, half = tid & 1;
    const unsigned short* src = qnb + ((size_t)b * 4096 + row0 + r) * 512 + h * 64 + half * 32;
    unsigned short* dst = As + r * 72 + half * 32;
    *(uint4*)dst = *(const uint4*)src;
    *(uint4*)(dst + 8) = *(const uint4*)(src + 8);
    *(uint4*)(dst + 16) = *(const uint4*)(src + 16);
    *(uint4*)(dst + 24) = *(const uint4*)(src + 24);
  }
  if (tid < 160) {
    const int r = tid >> 1, half = tid & 1;
    const unsigned short* src = khb + ((size_t)bh * 80 + r) * 64 + half * 32;
    unsigned short* dst = Bs + r * 72 + half * 32;
    *(uint4*)dst = *(const uint4*)src;
    *(uint4*)(dst + 8) = *(const uint4*)(src + 8);
    *(uint4*)(dst + 16) = *(const uint4*)(src + 16);
    *(uint4*)(dst + 24) = *(const uint4*)(src + 24);
  }
  __syncthreads();

  const int w = tid >> 6, lane = tid & 63;
  const int m16 = lane & 15, quad = lane >> 4;
  const unsigned short* aBase = As + (w * 32 + m16) * 72 + quad * 8;
  const unsigned short* bBase = Bs + m16 * 72 + quad * 8;
  bf16x8 af[2][2], bf[5][2];
#pragma unroll
  for (int mi = 0; mi < 2; ++mi)
#pragma unroll
    for (int kk = 0; kk < 2; ++kk)
      af[mi][kk] = *(const bf16x8*)(aBase + mi * 16 * 72 + kk * 32);
#pragma unroll
  for (int ni = 0; ni < 5; ++ni)
#pragma unroll
    for (int kk = 0; kk < 2; ++kk)
      bf[ni][kk] = *(const bf16x8*)(bBase + ni * 16 * 72 + kk * 32);
  __syncthreads();   // all frag reads done before LDS reuse

  const floatx4 zero4 = {0.f, 0.f, 0.f, 0.f};
  floatx4 acc[2][5];
#pragma unroll
  for (int mi = 0; mi < 2; ++mi)
#pragma unroll
    for (int ni = 0; ni < 5; ++ni) acc[mi][ni] = zero4;
#pragma unroll
  for (int kk = 0; kk < 2; ++kk)
#pragma unroll
    for (int mi = 0; mi < 2; ++mi)
#pragma unroll
      for (int ni = 0; ni < 5; ++ni)
        acc[mi][ni] = __builtin_amdgcn_mfma_f32_16x16x32_bf16(af[mi][kk], bf[ni][kk], acc[mi][ni], 0, 0, 0);

  const float ls = fminf(fmaxf(logit_scale[0], -2.0f), 2.0f);
  const float scale = expf(ls) * 0.125f;
  float nm[5];
#pragma unroll
  for (int ni = 0; ni < 5; ++ni) nm[ni] = negm[b * 80 + ni * 16 + m16];
#pragma unroll
  for (int mi = 0; mi < 2; ++mi)
#pragma unroll
    for (int r = 0; r < 4; ++r) {
      const int lr = w * 32 + quad * 4 + mi * 16 + r;   // 0..127
      const float ssv = ssq[(size_t)b * 4096 + row0 + lr];
      const float nsc = scale / fmaxf(sqrtf(ssv), 1e-6f);
#pragma unroll
      for (int ni = 0; ni < 5; ++ni)
        simt[lr * 81 + ni * 16 + m16] = acc[mi][ni][r] * nsc + nm[ni];
    }
  __syncthreads();

  // ---- phase 2: split top-3 scan (40 elems per half-thread) + static merge ----
  const int lr = tid >> 1, half = tid & 1;
  const int n = row0 + lr;
  const float* sp = simt + lr * 81;

  float m1 = -INFINITY, m2 = -INFINITY, m3 = -INFINITY, m4 = -INFINITY;
  int a1 = 0, a2 = 0, a3 = 0;
  const int tbase = half * 40;
  for (int tt = 0; tt < 40; ++tt) {
    const int t = tbase + tt;
    const float v = sp[t];
    const bool c1 = v > m1, c2 = v > m2, c3 = v > m3, c4 = v > m4;
    m4 = c4 ? (c3 ? m3 : v) : m4;
    m3 = c3 ? (c2 ? m2 : v) : m3;
    a3 = c3 ? (c2 ? a2 : t) : a3;
    m2 = c2 ? (c1 ? m1 : v) : m2;
    a2 = c2 ? (c1 ? a1 : t) : a2;
    m1 = c1 ? v : m1;
    a1 = c1 ? t : a1;
  }

  // exchange partner's top-4 (lanes 2k <-> 2k+1)
  const float pm1 = __shfl_xor(m1, 1, 64), pm2 = __shfl_xor(m2, 1, 64);
  const float pm3 = __shfl_xor(m3, 1, 64), pm4 = __shfl_xor(m4, 1, 64);
  const int pa1 = __shfl_xor(a1, 1, 64), pa2 = __shfl_xor(a2, 1, 64);
  const int pa3 = __shfl_xor(a3, 1, 64);

  // A = lower-half list (earlier indices), B = upper-half list
  const bool lo = (half == 0);
  const float A1 = lo ? m1 : pm1, A2 = lo ? m2 : pm2, A3 = lo ? m3 : pm3, A4 = lo ? m4 : pm4;
  const float B1 = lo ? pm1 : m1, B2 = lo ? pm2 : m2, B3 = lo ? pm3 : m3, B4 = lo ? pm4 : m4;
  const int Ai1 = lo ? a1 : pa1, Ai2 = lo ? a2 : pa2, Ai3 = lo ? a3 : pa3;
  const int Bi1 = lo ? pa1 : a1, Bi2 = lo ? pa2 : a2, Bi3 = lo ? pa3 : a3;

  // static 8-candidate insertion (A's fed first: earliest-index tie preference)
  m1 = -INFINITY; m2 = -INFINITY; m3 = -INFINITY; m4 = -INFINITY;
  a1 = 0; a2 = 0; a3 = 0;
#define INS3(v, idx)                                   \
  {                                                    \
    const bool c1 = (v) > m1, c2 = (v) > m2, c3 = (v) > m3, c4 = (v) > m4; \
    m4 = c4 ? (c3 ? m3 : (v)) : m4;                    \
    m3 = c3 ? (c2 ? m2 : (v)) : m3;                    \
    a3 = c3 ? (c2 ? a2 : (idx)) : a3;                  \
    m2 = c2 ? (c1 ? m1 : (v)) : m2;                    \
    a2 = c2 ? (c1 ? a1 : (idx)) : a2;                  \
    m1 = c1 ? (v) : m1;                                \
    a1 = c1 ? (idx) : a1;                              \
  }
  INS3(A1, Ai1) INS3(A2, Ai2) INS3(A3, Ai3) INS3(A4, 0)
  INS3(B1, Bi1) INS3(B2, Bi2) INS3(B3, Bi3) INS3(B4, 0)
#undef INS3

  const bool dead = (m1 == -INFINITY);
  if (dead) m1 = 0.0f;
  const bool tie = (!dead) && ((m1 == m2) || (m2 == m3) || (m3 == m4));

  const float d2 = m2 - m1, d3 = m3 - m1;
  const float e2 = __expf(d2), e3 = __expf(d3);   // exp(-inf)=0
  float s0 = 1.0f + e2 + e3;
  float s1 = ((e2 > 0.f) ? e2 * d2 : 0.f) + ((e3 > 0.f) ? e3 * d3 : 0.f);
  float cntf = 1.0f + ((e2 > 0.f) ? 1.f : 0.f) + ((e3 > 0.f) ? 1.f : 0.f);

  unsigned short* op = alignedb + ((size_t)b * 4096 + n) * 512 + h * 64 + half * 32;

  if (tie) {
    s0 = 0.f; s1 = 0.f; cntf = 0.f;
    float4 acc2[8];
#pragma unroll
    for (int i = 0; i < 8; ++i) acc2[i] = (float4){0.f, 0.f, 0.f, 0.f};
    for (int t = 0; t < 80; ++t) {
      const float v = sp[t];
      if (v >= m3) {
        const float e = expf(v - m1);
        if (e > 0.f) {
          s0 += e; s1 = fmaf(e, v - m1, s1); cntf += 1.f;
          const float4* vp = (const float4*)(vf + (size_t)(b * 77 + t) * 1024 + h * 64 + half * 32);
#pragma unroll
          for (int i = 0; i < 8; ++i) {
            const float4 x = vp[i];
            acc2[i].x = fmaf(e, x.x, acc2[i].x);
            acc2[i].y = fmaf(e, x.y, acc2[i].y);
            acc2[i].z = fmaf(e, x.z, acc2[i].z);
            acc2[i].w = fmaf(e, x.w, acc2[i].w);
          }
        }
      }
    }
    const float invt = 1.0f / s0;
#pragma unroll
    for (int i = 0; i < 4; ++i) {
      const float4 lov = acc2[2 * i], hiv = acc2[2 * i + 1];
      uint4 pk;
      pk.x = cvt2bf(lov.x * invt, lov.y * invt);
      pk.y = cvt2bf(lov.z * invt, lov.w * invt);
      pk.z = cvt2bf(hiv.x * invt, hiv.y * invt);
      pk.w = cvt2bf(hiv.z * invt, hiv.w * invt);
      *(uint4*)(op + i * 8) = pk;
    }
  } else {
    const float inv0 = 1.0f / s0;
    const float wA = dead ? 0.f : inv0;
    const float wB = e2 * inv0, wC = e3 * inv0;
    const float* v1p = vf + (size_t)(b * 77 + a1) * 1024 + h * 64 + half * 32;
    const float* v2p = vf + (size_t)(b * 77 + a2) * 1024 + h * 64 + half * 32;
    const float* v3p = vf + (size_t)(b * 77 + a3) * 1024 + h * 64 + half * 32;
#pragma unroll
    for (int i = 0; i < 4; ++i) {
      const float4 x0 = ((const float4*)v1p)[2 * i];
      const float4 x1 = ((const float4*)v1p)[2 * i + 1];
      const float4 y0 = ((const float4*)v2p)[2 * i];
      const float4 y1 = ((const float4*)v2p)[2 * i + 1];
      const float4 z0 = ((const float4*)v3p)[2 * i];
      const float4 z1 = ((const float4*)v3p)[2 * i + 1];
      float4 r0, r1;
      r0.x = fmaf(wC, z0.x, fmaf(wB, y0.x, wA * x0.x));
      r0.y = fmaf(wC, z0.y, fmaf(wB, y0.y, wA * x0.y));
      r0.z = fmaf(wC, z0.z, fmaf(wB, y0.z, wA * x0.z));
      r0.w = fmaf(wC, z0.w, fmaf(wB, y0.w, wA * x0.w));
      r1.x = fmaf(wC, z1.x, fmaf(wB, y1.x, wA * x1.x));
      r1.y = fmaf(wC, z1.y, fmaf(wB, y1.y, wA * x1.y));
      r1.z = fmaf(wC, z1.z, fmaf(wB, y1.z, wA * x1.z));
      r1.w = fmaf(wC, z1.w, fmaf(wB, y1.w, wA * x1.w));
      uint4 pk;
      pk.x = cvt2bf(r0.x, r0.y);
      pk.y = cvt2bf(r0.z, r0.w);
      pk.z = cvt2bf(r1.x, r1.y);
      pk.w = cvt2bf(r1.z, r1.w);
      *(uint4*)(op + i * 8) = pk;
    }
  }

  if (half == 0) {
    const float inv = 1.0f / s0;
    const float entn = (__logf(s0) - s1 * inv) + (77.0f - cntf) * 1.8420681e-7f;
    const float ent = fmaxf(entn / __logf(fmaxf(cntf, 2.0f)), 0.0f);
    float conf_h = fminf(fmaxf(inv * (1.0f - ent), 0.0f), 1.0f);
    if (dead) conf_h = 0.f;
    atomicAdd(confacc + (size_t)b * 4096 + n, conf_h * 0.125f);
  }
}

// ---------------- bf16 MFMA GEMM -----------------------------------------------
// Non-PIPE: single-buffer BK=64 (round-8 structure): [128][64] tiles, 8-chunk
//   XOR swizzle, 0 bank conflicts, 32 KB LDS.
// PIPE: 2-phase double-buffered BK=32: [2][128][32] tiles (same 32 KB LDS),
//   4-chunk XOR swizzle; prefetch tile t+1 into buf^1 BEFORE computing buf[cur];
//   ONE barrier per K-step; occupancy preserved.
// B staged column-permuted so each lane's 4 outputs are CONSECUTIVE columns.
// EPI: 1 bf16 out*(0.35+0.65*clamp(conf)); 2 gate epilogue; 3 bf16 GELU;
//      4 fp32 + residual; 5 bf16 out + per-row sum-of-squares atomics.
template <int EPI, int KC, bool PIPE = false>
__global__ __launch_bounds__(256)
void mfma_gemm(const unsigned short* __restrict__ A,
               const unsigned short* __restrict__ WT,
               const float* __restrict__ bias,
               void* __restrict__ outv, int M, int N,
               const unsigned short* __restrict__ e0b,
               const float* __restrict__ e1f,
               const float* __restrict__ e2f,
               const float* __restrict__ scf) {
  __shared__ __align__(16) unsigned short As[8192];   // 16 KB (both variants)
  __shared__ __align__(16) unsigned short Bs[8192];   // 16 KB
  const int tid = threadIdx.x;
  const int wid = tid >> 6, lane = tid & 63;
  const int wr = wid >> 1, wc = wid & 1;
  const int m16 = lane & 15, quad = lane >> 4;

  // XCD-chunked bijective block swizzle
  const int nwg = gridDim.x * gridDim.y;
  const int orig = blockIdx.y * gridDim.x + blockIdx.x;
  const int qq = nwg >> 3, rr = nwg & 7;
  const int xcd = orig & 7, base = orig >> 3;
  const int logical = (xcd < rr ? xcd * (qq + 1) : rr * (qq + 1) + (xcd - rr) * qq) + base;
  const int bx = logical % gridDim.x, by = logical / gridDim.x;
  const int row0 = by * 128, col0 = bx * 128;

  const floatx4 zero4 = {0.f, 0.f, 0.f, 0.f};
  floatx4 acc[4][4];
#pragma unroll
  for (int i = 0; i < 4; ++i)
#pragma unroll
    for (int j = 0; j < 4; ++j) acc[i][j] = zero4;

  if constexpr (!PIPE) {
    // ---- single-buffer BK=64, 8-chunk XOR swizzle (round-8) ----
    size_t aoff[4], boff[4];
    unsigned int ldso[4];
#pragma unroll
    for (int j = 0; j < 4; ++j) {
      const int s = wid * 64 + j * 256 + lane;
      const int r = s >> 3;
      const int gc = (s & 7) ^ (r & 7);
      aoff[j] = (size_t)(row0 + r) * KC + gc * 8;
      const int br = (r & 64) + 4 * (r & 15) + ((r >> 4) & 3);   // col-permuted B row
      boff[j] = (size_t)(col0 + br) * KC + gc * 8;
      ldso[j] = (unsigned int)s * 16;
    }
    for (int k0 = 0; k0 < KC; k0 += 64) {
      __syncthreads();
#pragma unroll
      for (int j = 0; j < 4; ++j) {
        __builtin_amdgcn_global_load_lds(GPTR(A + aoff[j] + k0), LPTR((char*)As + ldso[j]), 16, 0, 0);
        __builtin_amdgcn_global_load_lds(GPTR(WT + boff[j] + k0), LPTR((char*)Bs + ldso[j]), 16, 0, 0);
      }
      __syncthreads();
#pragma unroll
      for (int kk = 0; kk < 2; ++kk) {
        const int pc = (kk * 4 + quad) ^ (m16 & 7);
        bf16x8 af[4], bfr[4];
#pragma unroll
        for (int i = 0; i < 4; ++i) {
          af[i] = *(const bf16x8*)((const char*)As + (wr * 64 + i * 16 + m16) * 128 + pc * 16);
          bfr[i] = *(const bf16x8*)((const char*)Bs + (wc * 64 + i * 16 + m16) * 128 + pc * 16);
        }
#pragma unroll
        for (int mi = 0; mi < 4; ++mi)
#pragma unroll
          for (int ni = 0; ni < 4; ++ni)
            acc[mi][ni] = __builtin_amdgcn_mfma_f32_16x16x32_bf16(af[mi], bfr[ni], acc[mi][ni], 0, 0, 0);
      }
    }
  } else {
    // ---- double-buffer BK=32 2-phase pipeline, 4-chunk XOR swizzle ----
    size_t aoff[2], boff[2];
    unsigned int ldso[2];
#pragma unroll
    for (int j = 0; j < 2; ++j) {
      const int s = j * 256 + tid;     // 0..511
      const int r = s >> 2;            // row 0..127
      const int gc = (s & 3) ^ (r & 3);
      aoff[j] = (size_t)(row0 + r) * KC + gc * 8;
      const int br = (r & 64) + 4 * (r & 15) + ((r >> 4) & 3);   // col-permuted B row
      boff[j] = (size_t)(col0 + br) * KC + gc * 8;
      ldso[j] = (unsigned int)s * 16;
    }
    const int rq = quad ^ (m16 & 3);
    const int NT = KC / 32;
    // prologue: stage tile 0 into buffer 0
#pragma unroll
    for (int j = 0; j < 2; ++j) {
      __builtin_amdgcn_global_load_lds(GPTR(A + aoff[j]), LPTR((char*)As + ldso[j]), 16, 0, 0);
      __builtin_amdgcn_global_load_lds(GPTR(WT + boff[j]), LPTR((char*)Bs + ldso[j]), 16, 0, 0);
    }
    __syncthreads();
    int cur = 0;
    for (int t = 0; t < NT; ++t) {
      if (t + 1 < NT) {
        const size_t k0n = (size_t)(t + 1) * 32;
        const unsigned int bofs = (unsigned int)(cur ^ 1) * 8192;
#pragma unroll
        for (int j = 0; j < 2; ++j) {
          __builtin_amdgcn_global_load_lds(GPTR(A + aoff[j] + k0n), LPTR((char*)As + bofs + ldso[j]), 16, 0, 0);
          __builtin_amdgcn_global_load_lds(GPTR(WT + boff[j] + k0n), LPTR((char*)Bs + bofs + ldso[j]), 16, 0, 0);
        }
      }
      {
        const unsigned int cofs = (unsigned int)cur * 8192;
        bf16x8 af[4], bfr[4];
#pragma unroll
        for (int i = 0; i < 4; ++i) {
          af[i] = *(const bf16x8*)((const char*)As + cofs + (wr * 64 + i * 16 + m16) * 64 + rq * 16);
          bfr[i] = *(const bf16x8*)((const char*)Bs + cofs + (wc * 64 + i * 16 + m16) * 64 + rq * 16);
        }
#pragma unroll
        for (int mi = 0; mi < 4; ++mi)
#pragma unroll
          for (int ni = 0; ni < 4; ++ni)
            acc[mi][ni] = __builtin_amdgcn_mfma_f32_16x16x32_bf16(af[mi], bfr[ni], acc[mi][ni], 0, 0, 0);
      }
      if (t + 1 < NT) {
        __syncthreads();   // prefetched tile landed; all reads of buf[cur] done
        cur ^= 1;
      }
    }
  }

  float* outf = (float*)outv;
  unsigned short* outb = (unsigned short*)outv;
  const unsigned short* albf = (const unsigned short*)e1f;   // EPI==2: bf16 AO
  const int colb = col0 + wc * 64 + 4 * m16;   // 4 CONSECUTIVE output columns
  const float4 bbv = *(const float4*)(bias + colb);
  const float bb[4] = {bbv.x, bbv.y, bbv.z, bbv.w};
  const float alphav = (EPI == 2) ? scf[0] : 0.f;

#pragma unroll
  for (int mi = 0; mi < 4; ++mi) {
#pragma unroll
    for (int r = 0; r < 4; ++r) {
      const int row = row0 + wr * 64 + mi * 16 + quad * 4 + r;
      float o[4];
#pragma unroll
      for (int ni = 0; ni < 4; ++ni) o[ni] = acc[mi][ni][r] + bb[ni];
      const size_t basei = (size_t)row * N + colb;

      if (EPI == 5) {
        uint2 pk;
        pk.x = cvt2bf(o[0], o[1]);
        pk.y = cvt2bf(o[2], o[3]);
        *(uint2*)(outb + basei) = pk;
        float p = fmaf(o[0], o[0], fmaf(o[1], o[1], fmaf(o[2], o[2], o[3] * o[3])));
        p += __shfl_xor(p, 1, 64);
        p += __shfl_xor(p, 2, 64);
        p += __shfl_xor(p, 4, 64);
        p += __shfl_xor(p, 8, 64);
        if (m16 == 0) atomicAdd(const_cast<float*>(e1f) + row, p);
      } else if (EPI == 3) {
        uint2 pk;
        pk.x = cvt2bf(fast_gelu(o[0]), fast_gelu(o[1]));
        pk.y = cvt2bf(fast_gelu(o[2]), fast_gelu(o[3]));
        *(uint2*)(outb + basei) = pk;
      } else if (EPI == 1) {
        const float cm = fminf(fmaxf(e1f[row], 0.0f), 1.0f);
        const float rowscale = 0.35f + 0.65f * cm;
        uint2 pk;
        pk.x = cvt2bf(o[0] * rowscale, o[1] * rowscale);
        pk.y = cvt2bf(o[2] * rowscale, o[3] * rowscale);
        *(uint2*)(outb + basei) = pk;
      } else if (EPI == 2) {
        const float geo = fminf(fmaxf(e2f[row], 0.3f), 1.0f);
        const uint2 xpk = *(const uint2*)(e0b + basei);
        const uint2 apk = *(const uint2*)(albf + basei);
        const float xv[4] = {bf2f((unsigned short)xpk.x), bf2f((unsigned short)(xpk.x >> 16)),
                             bf2f((unsigned short)xpk.y), bf2f((unsigned short)(xpk.y >> 16))};
        const float av[4] = {bf2f((unsigned short)apk.x), bf2f((unsigned short)(apk.x >> 16)),
                             bf2f((unsigned short)apk.y), bf2f((unsigned short)(apk.y >> 16))};
        float4 ov;
        ov.x = xv[0] + alphav * fast_sigmoid(o[0]) * geo * av[0];
        ov.y = xv[1] + alphav * fast_sigmoid(o[1]) * geo * av[1];
        ov.z = xv[2] + alphav * fast_sigmoid(o[2]) * geo * av[2];
        ov.w = xv[3] + alphav * fast_sigmoid(o[3]) * geo * av[3];
        *(float4*)(outf + basei) = ov;
      } else {  // EPI == 4
        const float4 rv = *(const float4*)(e1f + basei);
        float4 ov;
        ov.x = o[0] + rv.x;
        ov.y = o[1] + rv.y;
        ov.z = o[2] + rv.z;
        ov.w = o[3] + rv.w;
        *(float4*)(outf + basei) = ov;
      }
    }
  }
}

extern "C" void kernel_launch(void* const* d_in, const int* in_sizes, int n_in,
                              void* d_out, int out_size, void* d_ws, size_t ws_size,
                              hipStream_t stream) {
  const float* visual = (const float*)d_in[0];
  const float* text   = (const float*)d_in[1];
  const float* geo    = (const float*)d_in[2];
  const float* ln1_w  = (const float*)d_in[3];
  const float* ln1_b  = (const float*)d_in[4];
  const float* wq     = (const float*)d_in[5];
  const float* bq     = (const float*)d_in[6];
  const float* wk     = (const float*)d_in[7];
  const float* bk     = (const float*)d_in[8];
  const float* wvw    = (const float*)d_in[9];
  const float* bv     = (const float*)d_in[10];
  const float* wo     = (const float*)d_in[11];
  const float* bo     = (const float*)d_in[12];
  const float* gate_w = (const float*)d_in[13];
  const float* gate_b = (const float*)d_in[14];
  const float* logit_scale = (const float*)d_in[15];
  const float* alpha  = (const float*)d_in[16];
  const float* ln2_w  = (const float*)d_in[17];
  const float* ln2_b  = (const float*)d_in[18];
  const float* ffn_w1 = (const float*)d_in[19];
  const float* ffn_b1 = (const float*)d_in[20];
  const float* ffn_w2 = (const float*)d_in[21];
  const float* ffn_b2 = (const float*)d_in[22];
  float* out = (float*)d_out;

  char* ws = (char*)d_ws;
  float* R0            = (float*)ws;                          // ALb bf16 -> GCH bf16
  float* BUF2          = (float*)(ws + 88080384);             // KV scratch -> y fp32
  unsigned short* Xb   = (unsigned short*)(ws + 155189248);   // 32 MB
  unsigned short* QNb  = (unsigned short*)(ws + 188743680);   // 32 MB q (-> AOb later)
  unsigned short* wqT  = (unsigned short*)(ws + 222298112);
  unsigned short* woT  = wqT + 262144;
  unsigned short* gateT = woT + 262144;
  unsigned short* w1T  = gateT + 262144;                      // [2048,512]
  unsigned short* w2T  = w1T + 1048576;                       // [512,2048]
  unsigned short* KHb  = w2T + 1048576;                       // [64,80,64] bf16
  float* NEGM = (float*)(ws + 230146048);                     // [8,80]
  float* CONF = (float*)(ws + 230148608);                     // [32768] conf accum
  float* SSQ  = (float*)(ws + 230279680);                     // [32768] ||q||^2

  // kv-projection scratch lives in the BUF2 region (dead after step 5/7):
  float* KV            = (float*)(ws + 88080384);             // [640,1024] fp32
  unsigned short* THi  = (unsigned short*)(ws + 88080384 + 2621440);   // [640,512]
  unsigned short* TLo  = THi + 640 * 512;
  unsigned short* WKVh = TLo + 640 * 512;                     // [1024,512]
  unsigned short* WKVl = WKVh + 1024 * 512;

  unsigned short* ALb = (unsigned short*)R0;   // aligned bf16 [32768,512]
  unsigned short* AOb = QNb;                   // q dead after fused kernel

  // weight transposes -> bf16 [N,K]
  transpose_bf16_kernel<<<dim3(16, 16), 256, 0, stream>>>(wq, wqT, 512, 512);
  transpose_bf16_kernel<<<dim3(16, 16), 256, 0, stream>>>(wo, woT, 512, 512);
  transpose_bf16_kernel<<<dim3(16, 16), 256, 0, stream>>>(gate_w, gateT, 512, 512);
  transpose_bf16_kernel<<<dim3(64, 16), 256, 0, stream>>>(ffn_w1, w1T, 512, 2048);
  transpose_bf16_kernel<<<dim3(16, 64), 256, 0, stream>>>(ffn_w2, w2T, 2048, 512);
  transpose_pair_kernel<<<dim3(16, 16), 256, 0, stream>>>(wk, WKVh, WKVl, 512, 512);
  transpose_pair_kernel<<<dim3(16, 16), 256, 0, stream>>>(wvw, WKVh + 512 * 512, WKVl + 512 * 512, 512, 512);

  // 1. x = LN1(visual) -> bf16 ; zero ss + conf accumulators
  ln_bf16_kernel<<<MTOT / 4, 256, 0, stream>>>(visual, ln1_w, ln1_b, Xb);
  zero_acc_kernel<<<128, 256, 0, stream>>>(SSQ, CONF);
  // 2. text -> hi/lo bf16 + pad mask; kv = text @ (wk|wv) via split-bf16 MFMA
  text_cvt_kernel<<<160, 256, 0, stream>>>(text, THi, TLo, NEGM);
  kv_gemm<<<dim3(8, 5), 256, 0, stream>>>(THi, TLo, WKVh, WKVl, bk, bv, KV);
  knorm_kernel<<<154, 256, 0, stream>>>(KV, KHb);
  kpad_zero_kernel<<<48, 256, 0, stream>>>(KHb, NEGM);
  // 3. q = x @ wq + bq -> bf16 QNb + per-row ss atomics (fused l2norm, part 1)
  mfma_gemm<5, 512><<<dim3(4, 256), 256, 0, stream>>>(Xb, wqT, bq, QNb, MTOT, 512,
                                                      nullptr, SSQ, nullptr, nullptr);
  // 4+5. FUSED sim -> LDS -> topk/softmax/conf/PV -> ALb bf16, CONF atomics
  sim_attn_kernel<<<dim3(32, 64), 256, 0, stream>>>(QNb, KHb, NEGM, SSQ, logit_scale,
                                                    KV + 512, ALb, CONF);
  // 6. alignedO = (aligned @ wo + bo) * (0.35+0.65*clamp(conf)) -> AOb bf16
  mfma_gemm<1, 512><<<dim3(4, 256), 256, 0, stream>>>(ALb, woT, bo, AOb, MTOT, 512,
                                                      nullptr, CONF, nullptr, nullptr);
  // 7. y = x + alpha*sigmoid(x@gate_w+gate_b)*geo*alignedO -> BUF2 (KV dead now)
  mfma_gemm<2, 512><<<dim3(4, 256), 256, 0, stream>>>(Xb, gateT, gate_b, BUF2, MTOT, 512,
                                                      Xb, (const float*)AOb, geo, alpha);
  // 8. h = LN2(y) -> Xb (bf16)
  ln_bf16_kernel<<<MTOT / 4, 256, 0, stream>>>(BUF2, ln2_w, ln2_b, Xb);
  // 9. FFN in 2 chunks of 16384 rows; GCH (bf16) overlays R0 (ALb dead)
  //    FFN1 uses the BK=32 2-phase pipelined variant (PIPE=true).
  unsigned short* GCH = (unsigned short*)R0;
  for (int ch = 0; ch < 2; ++ch) {
    const size_t off = (size_t)ch * 16384;
    mfma_gemm<3, 512, true><<<dim3(16, 128), 256, 0, stream>>>(Xb + off * 512, w1T, ffn_b1, GCH,
                                                               16384, 2048,
                                                               nullptr, nullptr, nullptr, nullptr);
    mfma_gemm<4, 2048><<<dim3(4, 128), 256, 0, stream>>>(GCH, w2T, ffn_b2, out + off * 512,
                                                         16384, 512,
                                                         nullptr, BUF2 + off * 512, nullptr, nullptr);
  }
}